// Round 9
// baseline (922.192 us; speedup 1.0000x reference)
//
#include <hip/hip_runtime.h>
#include <hip/hip_bf16.h>

typedef __attribute__((ext_vector_type(8))) short  short8;
typedef __attribute__((ext_vector_type(4))) float  f32x4;

#define MFMA16(A,B,C) __builtin_amdgcn_mfma_f32_16x16x32_bf16((A),(B),(C),0,0,0)

// ---- fp32 -> bf16 hi/lo split, pair-packed (cvt_pk path) ----
__device__ __forceinline__ void split2(float x0, float x1, unsigned &hp, unsigned &lp) {
    __hip_bfloat162 h = __float22bfloat162_rn(float2{x0, x1});
    union { __hip_bfloat162 b; unsigned u; } uh, ul;
    uh.b = h;
    float f0 = __bfloat162float(h.x);
    float f1 = __bfloat162float(h.y);
    ul.b = __float22bfloat162_rn(float2{x0 - f0, x1 - f1});
    hp = uh.u; lp = ul.u;
}

__device__ __forceinline__ void split8(const f32x4 a, const f32x4 b, short8 &h, short8 &l) {
    union { short8 s; unsigned u[4]; } H, L;
    split2(a[0], a[1], H.u[0], L.u[0]);
    split2(a[2], a[3], H.u[1], L.u[1]);
    split2(b[0], b[1], H.u[2], L.u[2]);
    split2(b[2], b[3], H.u[3], L.u[3]);
    h = H.s; l = L.s;
}

// XOR-swizzled byte offset inside a [16 rows][64 bf16] plane (row stride 128B).
__device__ __forceinline__ unsigned swz(unsigned row, unsigned colbyte) {
    return row * 128u + (colbyte ^ ((row & 7u) << 4));
}

// async global->LDS, 16B/lane. Global address is PER-LANE; LDS dest is the
// wave-uniform region base (HW writes base + lane*16).
__device__ __forceinline__ void gld16(const void* g, void* l) {
    __builtin_amdgcn_global_load_lds(
        (const __attribute__((address_space(1))) unsigned int*)g,
        (__attribute__((address_space(3))) unsigned int*)l, 16, 0, 0);
}

// Tree level, transposed-MFMA orientation. Block-shared gather staging via
// global_load_lds, double-buffered by parity, staged k+2 ahead (both LEAF and
// mid): staged buf[pb] is READ in phase1 (pre-barrier), RE-STAGED at phase2-top
// (post-barrier) for tile k+2 -> full-iteration in-flight window, race-free.
template<bool LEAF, bool FINAL, int MINW>
__global__ __launch_bounds__(256, MINW)
void grnn_mfma(const float* __restrict__ cont,   // ntiles*16 x 32 (fp32)
               const int*   __restrict__ child,  // ntiles*16 x 2
               const void*  __restrict__ ein_,   // emb_{j+1} hi/lo planes or contents8 fp32
               const float* __restrict__ Wu,     // 32 x 64
               const float* __restrict__ bu,     // 64
               const float* __restrict__ Wh,     // 192 x 64
               const float* __restrict__ bh,     // 64
               void*        __restrict__ eout_,  // hi/lo planes (fp32 if FINAL)
               int ntiles)
{
    constexpr int STG = LEAF ? 4096 : 8192;   // staged gather bytes per parity
    constexpr int NPL = LEAF ? 6 : 2;         // u planes per parity
    __shared__ __align__(16) char lds[2 * STG + 2 * NPL * 2048];
    char* upl0 = lds + 2 * STG;

    const int lane = threadIdx.x & 63;
    const int w    = threadIdx.x >> 6;
    const int cidx = lane & 15;
    const int g    = lane >> 4;

    // ---- weight fragments (hi/lo), transposed orientation ----
    short8 WhH[6], WhL[6], WuH, WuL;
#pragma unroll
    for (int s = 0; s < 6; ++s) {
        union { short8 s8; unsigned u[4]; } H, L;
#pragma unroll
        for (int q = 0; q < 4; ++q) {
            const int k = 32 * s + 8 * g + 2 * q;
            split2(Wh[k * 64 + 16 * w + cidx], Wh[(k + 1) * 64 + 16 * w + cidx], H.u[q], L.u[q]);
        }
        WhH[s] = H.s8; WhL[s] = L.s8;
    }
    {
        union { short8 s8; unsigned u[4]; } H, L;
#pragma unroll
        for (int q = 0; q < 4; ++q) {
            const int k = 8 * g + 2 * q;
            split2(Wu[k * 64 + 16 * w + cidx], Wu[(k + 1) * 64 + 16 * w + cidx], H.u[q], L.u[q]);
        }
        WuH = H.s8; WuL = L.s8;
    }
    const f32x4 bu4 = *(const f32x4*)(bu + 16 * w + 4 * g);
    const f32x4 bh4 = *(const f32x4*)(bh + 16 * w + 4 * g);

    const char* eb = (const char*)ein_;
    const unsigned colb = 32u * w + 8u * g;
    const int S = gridDim.x;

    // this wave's staging share
    const int side = w >> 1;   // 0: left child, 1: right child
    const int sub  = w & 1;    // 64B sub-segment of the row half

    // ---- prologue: stage tiles t and t+S, load cont(t) ----
    int t = blockIdx.x;
    {
        const int2 cA = *(const int2*)(child + 2 * (t * 16 + cidx));
        int t1 = (t + S < ntiles) ? t + S : t;
        const int2 cB = *(const int2*)(child + 2 * (t1 * 16 + cidx));
        if (LEAF) {
            gld16(eb + (size_t)(side ? cA.y : cA.x) * 128 + sub * 64 + g * 16,
                  lds + 0 * STG + (side * 2 + sub) * 1024);
            gld16(eb + (size_t)(side ? cB.y : cB.x) * 128 + sub * 64 + g * 16,
                  lds + 1 * STG + (side * 2 + sub) * 1024);
        } else {
            const char* sbA = eb + (size_t)(side ? cA.y : cA.x) * 256 + sub * 64 + g * 16;
            const char* sbB = eb + (size_t)(side ? cB.y : cB.x) * 256 + sub * 64 + g * 16;
            gld16(sbA,       lds + 0 * STG + (side * 4 + sub * 2 + 0) * 1024);
            gld16(sbA + 128, lds + 0 * STG + (side * 4 + sub * 2 + 1) * 1024);
            gld16(sbB,       lds + 1 * STG + (side * 4 + sub * 2 + 0) * 1024);
            gld16(sbB + 128, lds + 1 * STG + (side * 4 + sub * 2 + 1) * 1024);
        }
    }
    f32x4 cc0, cc1;
    {
        const f32x4* pc = (const f32x4*)(cont + (size_t)(t * 16 + cidx) * 32 + 8 * g);
        cc0 = pc[0]; cc1 = pc[1];
    }
    __syncthreads();   // prologue staging visible

    for (int k = 0; t < ntiles; t += S, ++k) {
        const int pb = k & 1;

        // prefetch: child idx for tile we stage this iteration (t+2S), next cont
        int ts = t + 2 * S;
        if (ts >= ntiles) ts = t;                         // clamped (dead dup)
        const int2 chN = *(const int2*)(child + 2 * (ts * 16 + cidx));
        int tn = (t + S < ntiles) ? t + S : t;
        f32x4 cn0, cn1;
        {
            const f32x4* pc = (const f32x4*)(cont + (size_t)(tn * 16 + cidx) * 32 + 8 * g);
            cn0 = pc[0]; cn1 = pc[1];
        }

        // ---- phase 1 ----
        char* ub = upl0 + pb * (NPL * 2048);
        f32x4 acc0 = bh4;
        f32x4 acc1 = {0.f, 0.f, 0.f, 0.f};
        short8 AH, AL;

        if (!LEAF) {
            // gather-slot MFMAs from staged fragments (consumed pre-barrier)
            const char* hb = lds + pb * STG;
            short8 fr[8];
#pragma unroll
            for (int q = 0; q < 8; ++q)
                fr[q] = *(const short8*)(hb + q * 1024 + 16 * lane);
            // u-GEMM (independent chain, overlaps the ds_read latency)
            split8(cc0, cc1, AH, AL);
            f32x4 ua = bu4;
            ua = MFMA16(WuH, AH, ua);
            ua = MFMA16(WuL, AH, ua);
            ua = MFMA16(WuH, AL, ua);
            {
                const unsigned off = swz(cidx, colb);
                unsigned h0, l0, h1, l1;
                split2(fmaxf(ua[0], 0.f), fmaxf(ua[1], 0.f), h0, l0);
                split2(fmaxf(ua[2], 0.f), fmaxf(ua[3], 0.f), h1, l1);
                *(uint2*)(ub + 0 * 2048 + off) = uint2{h0, h1};
                *(uint2*)(ub + 1 * 2048 + off) = uint2{l0, l1};
            }
#pragma unroll
            for (int sd = 0; sd < 2; ++sd) {
#pragma unroll
                for (int s = 0; s < 2; ++s) {
                    const short8 aH = fr[sd * 4 + s * 2 + 0];
                    const short8 aL = fr[sd * 4 + s * 2 + 1];
                    const int Sl = 2 * sd + s;
                    f32x4 &acc = sd ? acc1 : acc0;
                    acc = MFMA16(WhH[Sl], aH, acc);
                    acc = MFMA16(WhL[Sl], aH, acc);
                    acc = MFMA16(WhH[Sl], aL, acc);
                }
            }
        } else {
            // u-GEMM for this tile's own rows
            split8(cc0, cc1, AH, AL);
            f32x4 ua = bu4;
            ua = MFMA16(WuH, AH, ua);
            ua = MFMA16(WuL, AH, ua);
            ua = MFMA16(WuH, AL, ua);
            {
                const unsigned off = swz(cidx, colb);
                unsigned h0, l0, h1, l1;
                split2(fmaxf(ua[0], 0.f), fmaxf(ua[1], 0.f), h0, l0);
                split2(fmaxf(ua[2], 0.f), fmaxf(ua[3], 0.f), h1, l1);
                *(uint2*)(ub + 4 * 2048 + off) = uint2{h0, h1};
                *(uint2*)(ub + 5 * 2048 + off) = uint2{l0, l1};
            }
            // uL, uR from staged fp32 x-rows (staged at iter k-2 into buf pb)
            const char* xb = lds + pb * STG;
            const unsigned o0 = 512u * (g & 1) + 16u * cidx;
            const unsigned rg = (unsigned)(g >> 1) * 1024u;
            const unsigned off = swz(cidx, colb);
#pragma unroll
            for (int sd = 0; sd < 2; ++sd) {
                const char* base = xb + sd * 2048 + rg;
                const f32x4 a = *(const f32x4*)(base + o0);
                const f32x4 b = *(const f32x4*)(base + o0 + 256);
                split8(a, b, AH, AL);
                f32x4 ux = bu4;
                ux = MFMA16(WuH, AH, ux);
                ux = MFMA16(WuL, AH, ux);
                ux = MFMA16(WuH, AL, ux);
                unsigned h0, l0, h1, l1;
                split2(fmaxf(ux[0], 0.f), fmaxf(ux[1], 0.f), h0, l0);
                split2(fmaxf(ux[2], 0.f), fmaxf(ux[3], 0.f), h1, l1);
                *(uint2*)(ub + (2 * sd + 0) * 2048 + off) = uint2{h0, h1};
                *(uint2*)(ub + (2 * sd + 1) * 2048 + off) = uint2{l0, l1};
            }
        }
        __syncthreads();   // u planes visible; staged buf[pb] fully consumed

        // ---- phase 2 ----
        // re-stage buf[pb] for tile k+2 (drains at NEXT barrier, consumed k+2)
        if (LEAF) {
            gld16(eb + (size_t)(side ? chN.y : chN.x) * 128 + sub * 64 + g * 16,
                  lds + pb * STG + (side * 2 + sub) * 1024);
        } else {
            const char* sN = eb + (size_t)(side ? chN.y : chN.x) * 256 + sub * 64 + g * 16;
            gld16(sN,       lds + pb * STG + (side * 4 + sub * 2 + 0) * 1024);
            gld16(sN + 128, lds + pb * STG + (side * 4 + sub * 2 + 1) * 1024);
        }

        if (LEAF) {
#pragma unroll
            for (int q = 0; q < 3; ++q) {
#pragma unroll
                for (int s = 0; s < 2; ++s) {
                    const short8 aH = *(const short8*)(ub + (2 * q + 0) * 2048 + swz(cidx, 64 * s + 16 * g));
                    const short8 aL = *(const short8*)(ub + (2 * q + 1) * 2048 + swz(cidx, 64 * s + 16 * g));
                    const int Sl = 2 * q + s;
                    f32x4 &acc = s ? acc1 : acc0;
                    acc = MFMA16(WhH[Sl], aH, acc);
                    acc = MFMA16(WhL[Sl], aH, acc);
                    acc = MFMA16(WhH[Sl], aL, acc);
                }
            }
        } else {
#pragma unroll
            for (int s = 0; s < 2; ++s) {
                const short8 aH = *(const short8*)(ub + 0 * 2048 + swz(cidx, 64 * s + 16 * g));
                const short8 aL = *(const short8*)(ub + 1 * 2048 + swz(cidx, 64 * s + 16 * g));
                const int Sl = 4 + s;
                f32x4 &acc = s ? acc1 : acc0;
                acc = MFMA16(WhH[Sl], aH, acc);
                acc = MFMA16(WhL[Sl], aH, acc);
                acc = MFMA16(WhH[Sl], aL, acc);
            }
        }

        // ---- store: lane holds out[row=cidx][cols 16w+4g .. +3] ----
        if (FINAL) {
            float* out = (float*)eout_;
            f32x4 v;
#pragma unroll
            for (int i = 0; i < 4; ++i) v[i] = fmaxf(acc0[i] + acc1[i], 0.f);
            *(f32x4*)(out + (size_t)(t * 16 + cidx) * 64 + 16 * w + 4 * g) = v;
        } else {
            char* out = (char*)eout_;
            const size_t rb = (size_t)(t * 16 + cidx) * 256;
            unsigned h0, l0, h1, l1;
            split2(fmaxf(acc0[0] + acc1[0], 0.f), fmaxf(acc0[1] + acc1[1], 0.f), h0, l0);
            split2(fmaxf(acc0[2] + acc1[2], 0.f), fmaxf(acc0[3] + acc1[3], 0.f), h1, l1);
            *(uint2*)(out + rb + colb)       = uint2{h0, h1};
            *(uint2*)(out + rb + 128 + colb) = uint2{l0, l1};
        }

        cc0 = cn0; cc1 = cn1;
    }
}

extern "C" void kernel_launch(void* const* d_in, const int* in_sizes, int n_in,
                              void* d_out, int out_size, void* d_ws, size_t ws_size,
                              hipStream_t stream) {
    // inputs: contents0..8 = d_in[0..8], children0..7 = d_in[9..16],
    //         Wu = d_in[17], bu = d_in[18], Wh = d_in[19], bh = d_in[20]
    const float* Wu = (const float*)d_in[17];
    const float* bu = (const float*)d_in[18];
    const float* Wh = (const float*)d_in[19];
    const float* bh = (const float*)d_in[20];

    // emb_j stored as bf16 hi/lo planes, 256B/row
    void* bufA = d_ws;                               // emb7/5/3/1
    void* bufB = (char*)d_ws + (size_t)268435456;    // emb6/4/2

    const void* ein = d_in[8];  // contents8 (fp32) for the fused leaf level
    for (int j = 7; j >= 0; --j) {
        const int n      = in_sizes[j] / 32;
        const int ntiles = n / 16;
        void* eout = (j == 0) ? d_out : ((j & 1) ? bufA : bufB);
        int blocks = ntiles < 4096 ? ntiles : 4096;
        const float* cont  = (const float*)d_in[j];
        const int*   child = (const int*)d_in[9 + j];
        if (j == 7)
            grnn_mfma<true,  false, 5><<<blocks, 256, 0, stream>>>(cont, child, ein, Wu, bu, Wh, bh, eout, ntiles);
        else if (j == 0)
            grnn_mfma<false, true,  6><<<blocks, 256, 0, stream>>>(cont, child, ein, Wu, bu, Wh, bh, eout, ntiles);
        else
            grnn_mfma<false, false, 6><<<blocks, 256, 0, stream>>>(cont, child, ein, Wu, bu, Wh, bh, eout, ntiles);
        ein = eout;
    }
}

// Round 10
// 544.397 us; speedup vs baseline: 1.6940x; 1.6940x over previous
//
#include <hip/hip_runtime.h>
#include <hip/hip_bf16.h>

typedef __attribute__((ext_vector_type(8))) short  short8;
typedef __attribute__((ext_vector_type(4))) float  f32x4;

#define MFMA16(A,B,C) __builtin_amdgcn_mfma_f32_16x16x32_bf16((A),(B),(C),0,0,0)

// ---- fp32 -> bf16 hi/lo split, pair-packed (cvt_pk path) ----
__device__ __forceinline__ void split2(float x0, float x1, unsigned &hp, unsigned &lp) {
    __hip_bfloat162 h = __float22bfloat162_rn(float2{x0, x1});
    union { __hip_bfloat162 b; unsigned u; } uh, ul;
    uh.b = h;
    float f0 = __bfloat162float(h.x);
    float f1 = __bfloat162float(h.y);
    ul.b = __float22bfloat162_rn(float2{x0 - f0, x1 - f1});
    hp = uh.u; lp = ul.u;
}

__device__ __forceinline__ void split8(const f32x4 a, const f32x4 b, short8 &h, short8 &l) {
    union { short8 s; unsigned u[4]; } H, L;
    split2(a[0], a[1], H.u[0], L.u[0]);
    split2(a[2], a[3], H.u[1], L.u[1]);
    split2(b[0], b[1], H.u[2], L.u[2]);
    split2(b[2], b[3], H.u[3], L.u[3]);
    h = H.s; l = L.s;
}

// XOR-swizzled byte offset inside a [16 rows][64 bf16] plane (row stride 128B).
__device__ __forceinline__ unsigned swz(unsigned row, unsigned colbyte) {
    return row * 128u + (colbyte ^ ((row & 7u) << 4));
}

// async global->LDS, 16B/lane. Global address is PER-LANE; LDS dest is the
// wave-uniform region base (HW writes base + lane*16).
__device__ __forceinline__ void gld16(const void* g, void* l) {
    __builtin_amdgcn_global_load_lds(
        (const __attribute__((address_space(1))) unsigned int*)g,
        (__attribute__((address_space(3))) unsigned int*)l, 16, 0, 0);
}

// Tree level, transposed-MFMA orientation (R8 schedule) + split-dedup:
// the per-tile fp32->bf16hi/lo splits (wave-invariant B-fragments) are done
// ONCE per block: during phase2(k), waves 0/1/2 convert tile k+1's sources
// (cont / xL / xR; mids: wave0 converts cont) into LDS "frag planes" laid out
// in per-lane fragment order; phase1(k+1) feeds MFMA straight from ds_read.
template<bool LEAF, bool FINAL>
__global__ __launch_bounds__(256, 4)
void grnn_mfma(const float* __restrict__ cont,   // ntiles*16 x 32 (fp32)
               const int*   __restrict__ child,  // ntiles*16 x 2
               const void*  __restrict__ ein_,   // emb_{j+1} hi/lo planes or contents8 fp32
               const float* __restrict__ Wu,     // 32 x 64
               const float* __restrict__ bu,     // 64
               const float* __restrict__ Wh,     // 192 x 64
               const float* __restrict__ bh,     // 64
               void*        __restrict__ eout_,  // hi/lo planes (fp32 if FINAL)
               int ntiles)
{
    constexpr int STG = LEAF ? 4096 : 8192;   // staged gather bytes per parity
    constexpr int NPL = LEAF ? 6 : 2;         // u planes per parity
    constexpr int NFP = LEAF ? 3 : 1;         // frag planes: cont[,xL,xR]
    __shared__ __align__(16) char lds[2 * STG + 2 * NPL * 2048 + NFP * 2048];
    char* upl0 = lds + 2 * STG;
    char* fpl  = lds + 2 * STG + 2 * NPL * 2048;

    const int lane = threadIdx.x & 63;
    const int w    = threadIdx.x >> 6;
    const int cidx = lane & 15;
    const int g    = lane >> 4;

    // ---- weight fragments (hi/lo), transposed orientation ----
    short8 WhH[6], WhL[6], WuH, WuL;
#pragma unroll
    for (int s = 0; s < 6; ++s) {
        union { short8 s8; unsigned u[4]; } H, L;
#pragma unroll
        for (int q = 0; q < 4; ++q) {
            const int k = 32 * s + 8 * g + 2 * q;
            split2(Wh[k * 64 + 16 * w + cidx], Wh[(k + 1) * 64 + 16 * w + cidx], H.u[q], L.u[q]);
        }
        WhH[s] = H.s8; WhL[s] = L.s8;
    }
    {
        union { short8 s8; unsigned u[4]; } H, L;
#pragma unroll
        for (int q = 0; q < 4; ++q) {
            const int k = 8 * g + 2 * q;
            split2(Wu[k * 64 + 16 * w + cidx], Wu[(k + 1) * 64 + 16 * w + cidx], H.u[q], L.u[q]);
        }
        WuH = H.s8; WuL = L.s8;
    }
    const f32x4 bu4 = *(const f32x4*)(bu + 16 * w + 4 * g);
    const f32x4 bh4 = *(const f32x4*)(bh + 16 * w + 4 * g);

    const char* eb = (const char*)ein_;
    const unsigned colb = 32u * w + 8u * g;
    const int S = gridDim.x;

    // staging shares + fragment-plane offsets
    const int side = w >> 1;
    const int sub  = w & 1;
    const unsigned fo = (unsigned)g * 256u + (unsigned)cidx * 16u;  // frag slot
    const unsigned o0 = 512u * (g & 1) + 16u * cidx;                // fp32 x-frag
    const unsigned rg = (unsigned)(g >> 1) * 1024u;

    // ---- prologue: stage tiles t and t+S; wave0 loads cont(t) ----
    int t = blockIdx.x;
    {
        const int2 cA = *(const int2*)(child + 2 * (t * 16 + cidx));
        int t1 = (t + S < ntiles) ? t + S : t;
        const int2 cB = *(const int2*)(child + 2 * (t1 * 16 + cidx));
        if (LEAF) {
            gld16(eb + (size_t)(side ? cA.y : cA.x) * 128 + sub * 64 + g * 16,
                  lds + 0 * STG + (side * 2 + sub) * 1024);
            gld16(eb + (size_t)(side ? cB.y : cB.x) * 128 + sub * 64 + g * 16,
                  lds + 1 * STG + (side * 2 + sub) * 1024);
        } else {
            const char* sbA = eb + (size_t)(side ? cA.y : cA.x) * 256 + sub * 64 + g * 16;
            const char* sbB = eb + (size_t)(side ? cB.y : cB.x) * 256 + sub * 64 + g * 16;
            gld16(sbA,       lds + 0 * STG + (side * 4 + sub * 2 + 0) * 1024);
            gld16(sbA + 128, lds + 0 * STG + (side * 4 + sub * 2 + 1) * 1024);
            gld16(sbB,       lds + 1 * STG + (side * 4 + sub * 2 + 0) * 1024);
            gld16(sbB + 128, lds + 1 * STG + (side * 4 + sub * 2 + 1) * 1024);
        }
    }
    f32x4 c0, c1;
    if (w == 0) {
        const f32x4* pc = (const f32x4*)(cont + (size_t)(t * 16 + cidx) * 32 + 8 * g);
        c0 = pc[0]; c1 = pc[1];
    }
    __syncthreads();   // prologue staging + c0 visible (vmcnt drained)

    // prologue split-jobs: frag planes for tile 0
    if (w == 0) {
        short8 AH, AL;
        split8(c0, c1, AH, AL);
        *(short8*)(fpl + fo)        = AH;
        *(short8*)(fpl + 1024 + fo) = AL;
    } else if (LEAF && w <= 2) {
        const char* xb = lds + 0 * STG + (w - 1) * 2048;
        const f32x4 a = *(const f32x4*)(xb + rg + o0);
        const f32x4 b = *(const f32x4*)(xb + rg + o0 + 256);
        short8 AH, AL;
        split8(a, b, AH, AL);
        *(short8*)(fpl + w * 2048 + fo)        = AH;
        *(short8*)(fpl + w * 2048 + 1024 + fo) = AL;
    }
    __syncthreads();

    for (int k = 0; t < ntiles; t += S, ++k) {
        const int pb = k & 1;
        char* ub = upl0 + pb * (NPL * 2048);

        // prefetch: child idx for the staging tile, wave0 loads cont(t+S)
        int ts = LEAF ? (t + 2 * S) : (t + S);
        if (ts >= ntiles) ts = t;
        const int2 chN = *(const int2*)(child + 2 * (ts * 16 + cidx));
        int tn = (t + S < ntiles) ? t + S : t;
        if (w == 0) {
            const f32x4* pc = (const f32x4*)(cont + (size_t)(tn * 16 + cidx) * 32 + 8 * g);
            c0 = pc[0]; c1 = pc[1];
        }

        // ---- phase 1: u-GEMMs from frag planes; relu+split into u planes[pb] ----
        {
            const short8 aH = *(const short8*)(fpl + fo);
            const short8 aL = *(const short8*)(fpl + 1024 + fo);
            f32x4 ua = bu4;
            ua = MFMA16(WuH, aH, ua);
            ua = MFMA16(WuL, aH, ua);
            ua = MFMA16(WuH, aL, ua);
            const unsigned off = swz(cidx, colb);
            unsigned h0, l0, h1, l1;
            split2(fmaxf(ua[0], 0.f), fmaxf(ua[1], 0.f), h0, l0);
            split2(fmaxf(ua[2], 0.f), fmaxf(ua[3], 0.f), h1, l1);
            *(uint2*)(ub + (NPL - 2) * 2048 + off) = uint2{h0, h1};
            *(uint2*)(ub + (NPL - 1) * 2048 + off) = uint2{l0, l1};
            if (LEAF) {
#pragma unroll
                for (int sd = 0; sd < 2; ++sd) {
                    const short8 xH = *(const short8*)(fpl + (1 + sd) * 2048 + fo);
                    const short8 xL = *(const short8*)(fpl + (1 + sd) * 2048 + 1024 + fo);
                    f32x4 ux = bu4;
                    ux = MFMA16(WuH, xH, ux);
                    ux = MFMA16(WuL, xH, ux);
                    ux = MFMA16(WuH, xL, ux);
                    split2(fmaxf(ux[0], 0.f), fmaxf(ux[1], 0.f), h0, l0);
                    split2(fmaxf(ux[2], 0.f), fmaxf(ux[3], 0.f), h1, l1);
                    *(uint2*)(ub + (2 * sd + 0) * 2048 + off) = uint2{h0, h1};
                    *(uint2*)(ub + (2 * sd + 1) * 2048 + off) = uint2{l0, l1};
                }
            }
        }
        __syncthreads();   // A: u planes visible; frag planes fully consumed

        // ---- phase 2 ----
        // re-stage (leaf: tile k+2 -> buf[pb]; mid: tile k+1 -> buf[pb^1])
        if (LEAF) {
            gld16(eb + (size_t)(side ? chN.y : chN.x) * 128 + sub * 64 + g * 16,
                  lds + pb * STG + (side * 2 + sub) * 1024);
        } else {
            const char* sN = eb + (size_t)(side ? chN.y : chN.x) * 256 + sub * 64 + g * 16;
            gld16(sN,       lds + (pb ^ 1) * STG + (side * 4 + sub * 2 + 0) * 1024);
            gld16(sN + 128, lds + (pb ^ 1) * STG + (side * 4 + sub * 2 + 1) * 1024);
        }

        f32x4 acc0 = bh4;
        f32x4 acc1 = {0.f, 0.f, 0.f, 0.f};
        if (LEAF) {
#pragma unroll
            for (int q = 0; q < 3; ++q) {
#pragma unroll
                for (int s = 0; s < 2; ++s) {
                    const short8 aH = *(const short8*)(ub + (2 * q + 0) * 2048 + swz(cidx, 64 * s + 16 * g));
                    const short8 aL = *(const short8*)(ub + (2 * q + 1) * 2048 + swz(cidx, 64 * s + 16 * g));
                    const int Sl = 2 * q + s;
                    f32x4 &acc = s ? acc1 : acc0;
                    acc = MFMA16(WhH[Sl], aH, acc);
                    acc = MFMA16(WhL[Sl], aH, acc);
                    acc = MFMA16(WhH[Sl], aL, acc);
                }
            }
        } else {
            const char* hb = lds + pb * STG;
#pragma unroll
            for (int sd = 0; sd < 2; ++sd) {
#pragma unroll
                for (int s = 0; s < 2; ++s) {
                    const short8 aH = *(const short8*)(hb + (sd * 4 + s * 2 + 0) * 1024 + 16 * lane);
                    const short8 aL = *(const short8*)(hb + (sd * 4 + s * 2 + 1) * 1024 + 16 * lane);
                    const int Sl = 2 * sd + s;
                    f32x4 &acc = sd ? acc1 : acc0;
                    acc = MFMA16(WhH[Sl], aH, acc);
                    acc = MFMA16(WhL[Sl], aH, acc);
                    acc = MFMA16(WhH[Sl], aL, acc);
                }
            }
#pragma unroll
            for (int s = 0; s < 2; ++s) {
                const short8 aH = *(const short8*)(ub + 0 * 2048 + swz(cidx, 64 * s + 16 * g));
                const short8 aL = *(const short8*)(ub + 1 * 2048 + swz(cidx, 64 * s + 16 * g));
                const int Sl = 4 + s;
                f32x4 &acc = s ? acc1 : acc0;
                acc = MFMA16(WhH[Sl], aH, acc);
                acc = MFMA16(WhL[Sl], aH, acc);
                acc = MFMA16(WhH[Sl], aL, acc);
            }
        }

        // split-jobs: frag planes for tile k+1 (written post-A, read post-B)
        if (w == 0) {
            short8 AH, AL;
            split8(c0, c1, AH, AL);
            *(short8*)(fpl + fo)        = AH;
            *(short8*)(fpl + 1024 + fo) = AL;
        } else if (LEAF && w <= 2) {
            const char* xb = lds + (pb ^ 1) * STG + (w - 1) * 2048;  // tile k+1's x
            const f32x4 a = *(const f32x4*)(xb + rg + o0);
            const f32x4 b = *(const f32x4*)(xb + rg + o0 + 256);
            short8 AH, AL;
            split8(a, b, AH, AL);
            *(short8*)(fpl + w * 2048 + fo)        = AH;
            *(short8*)(fpl + w * 2048 + 1024 + fo) = AL;
        }

        // ---- store: lane holds out[row=cidx][cols 16w+4g .. +3] ----
        if (FINAL) {
            float* out = (float*)eout_;
            f32x4 v;
#pragma unroll
            for (int i = 0; i < 4; ++i) v[i] = fmaxf(acc0[i] + acc1[i], 0.f);
            *(f32x4*)(out + (size_t)(t * 16 + cidx) * 64 + 16 * w + 4 * g) = v;
        } else {
            char* out = (char*)eout_;
            const size_t rb = (size_t)(t * 16 + cidx) * 256;
            unsigned h0, l0, h1, l1;
            split2(fmaxf(acc0[0] + acc1[0], 0.f), fmaxf(acc0[1] + acc1[1], 0.f), h0, l0);
            split2(fmaxf(acc0[2] + acc1[2], 0.f), fmaxf(acc0[3] + acc1[3], 0.f), h1, l1);
            *(uint2*)(out + rb + colb)       = uint2{h0, h1};
            *(uint2*)(out + rb + 128 + colb) = uint2{l0, l1};
        }
        __syncthreads();   // B
    }
}

extern "C" void kernel_launch(void* const* d_in, const int* in_sizes, int n_in,
                              void* d_out, int out_size, void* d_ws, size_t ws_size,
                              hipStream_t stream) {
    // inputs: contents0..8 = d_in[0..8], children0..7 = d_in[9..16],
    //         Wu = d_in[17], bu = d_in[18], Wh = d_in[19], bh = d_in[20]
    const float* Wu = (const float*)d_in[17];
    const float* bu = (const float*)d_in[18];
    const float* Wh = (const float*)d_in[19];
    const float* bh = (const float*)d_in[20];

    // emb_j stored as bf16 hi/lo planes, 256B/row
    void* bufA = d_ws;                               // emb7/5/3/1
    void* bufB = (char*)d_ws + (size_t)268435456;    // emb6/4/2

    const void* ein = d_in[8];  // contents8 (fp32) for the fused leaf level
    for (int j = 7; j >= 0; --j) {
        const int n      = in_sizes[j] / 32;
        const int ntiles = n / 16;
        void* eout = (j == 0) ? d_out : ((j & 1) ? bufA : bufB);
        int blocks = ntiles < 4096 ? ntiles : 4096;
        const float* cont  = (const float*)d_in[j];
        const int*   child = (const int*)d_in[9 + j];
        if (j == 7)
            grnn_mfma<true,  false><<<blocks, 256, 0, stream>>>(cont, child, ein, Wu, bu, Wh, bh, eout, ntiles);
        else if (j == 0)
            grnn_mfma<false, true ><<<blocks, 256, 0, stream>>>(cont, child, ein, Wu, bu, Wh, bh, eout, ntiles);
        else
            grnn_mfma<false, false><<<blocks, 256, 0, stream>>>(cont, child, ein, Wu, bu, Wh, bh, eout, ntiles);
        ein = eout;
    }
}

// Round 11
// 523.864 us; speedup vs baseline: 1.7604x; 1.0392x over previous
//
#include <hip/hip_runtime.h>
#include <hip/hip_bf16.h>

typedef __attribute__((ext_vector_type(8))) short  short8;
typedef __attribute__((ext_vector_type(4))) float  f32x4;

#define MFMA16(A,B,C) __builtin_amdgcn_mfma_f32_16x16x32_bf16((A),(B),(C),0,0,0)

// LDS-visibility barrier WITHOUT the vmcnt drain: staged global_load_lds ops
// stay in flight across it. (T3/T4: never drain vmcnt to 0 in the main loop.)
__device__ __forceinline__ void barrier_nv() {
    __builtin_amdgcn_sched_barrier(0);
    asm volatile("s_waitcnt lgkmcnt(0)" ::: "memory");
    __builtin_amdgcn_s_barrier();
    __builtin_amdgcn_sched_barrier(0);
}
// counted vmem wait: proves all but the N newest vmem ops complete.
#define VM_WAIT(N) do { asm volatile("s_waitcnt vmcnt(" #N ")" ::: "memory"); \
                        __builtin_amdgcn_sched_barrier(0); } while (0)

// ---- fp32 -> bf16 hi/lo split, pair-packed (cvt_pk path) ----
__device__ __forceinline__ void split2(float x0, float x1, unsigned &hp, unsigned &lp) {
    __hip_bfloat162 h = __float22bfloat162_rn(float2{x0, x1});
    union { __hip_bfloat162 b; unsigned u; } uh, ul;
    uh.b = h;
    float f0 = __bfloat162float(h.x);
    float f1 = __bfloat162float(h.y);
    ul.b = __float22bfloat162_rn(float2{x0 - f0, x1 - f1});
    hp = uh.u; lp = ul.u;
}

__device__ __forceinline__ void split8(const f32x4 a, const f32x4 b, short8 &h, short8 &l) {
    union { short8 s; unsigned u[4]; } H, L;
    split2(a[0], a[1], H.u[0], L.u[0]);
    split2(a[2], a[3], H.u[1], L.u[1]);
    split2(b[0], b[1], H.u[2], L.u[2]);
    split2(b[2], b[3], H.u[3], L.u[3]);
    h = H.s; l = L.s;
}

// XOR-swizzled byte offset inside a [16 rows][64 bf16] plane (row stride 128B).
__device__ __forceinline__ unsigned swz(unsigned row, unsigned colbyte) {
    return row * 128u + (colbyte ^ ((row & 7u) << 4));
}

// async global->LDS, 16B/lane. Global address is PER-LANE; LDS dest is the
// wave-uniform region base (HW writes base + lane*16).
__device__ __forceinline__ void gld16(const void* g, void* l) {
    __builtin_amdgcn_global_load_lds(
        (const __attribute__((address_space(1))) unsigned int*)g,
        (__attribute__((address_space(3))) unsigned int*)l, 16, 0, 0);
}

// Tree level, transposed-MFMA orientation (R10 structure) with non-draining
// loop barriers + counted vmcnt waits: staging issued in phase2(k-1) is only
// awaited at its consumption point in phase2(k) -> full-iteration window.
template<bool LEAF, bool FINAL>
__global__ __launch_bounds__(256, 4)
void grnn_mfma(const float* __restrict__ cont,   // ntiles*16 x 32 (fp32)
               const int*   __restrict__ child,  // ntiles*16 x 2
               const void*  __restrict__ ein_,   // emb_{j+1} hi/lo planes or contents8 fp32
               const float* __restrict__ Wu,     // 32 x 64
               const float* __restrict__ bu,     // 64
               const float* __restrict__ Wh,     // 192 x 64
               const float* __restrict__ bh,     // 64
               void*        __restrict__ eout_,  // hi/lo planes (fp32 if FINAL)
               int ntiles)
{
    constexpr int STG = LEAF ? 4096 : 8192;   // staged gather bytes per parity
    constexpr int NPL = LEAF ? 6 : 2;         // u planes per parity
    constexpr int NFP = LEAF ? 3 : 1;         // frag planes: cont[,xL,xR]
    __shared__ __align__(16) char lds[2 * STG + 2 * NPL * 2048 + NFP * 2048];
    char* upl0 = lds + 2 * STG;
    char* fpl  = lds + 2 * STG + 2 * NPL * 2048;

    const int lane = threadIdx.x & 63;
    const int w    = threadIdx.x >> 6;
    const int cidx = lane & 15;
    const int g    = lane >> 4;

    // ---- weight fragments (hi/lo), transposed orientation ----
    short8 WhH[6], WhL[6], WuH, WuL;
#pragma unroll
    for (int s = 0; s < 6; ++s) {
        union { short8 s8; unsigned u[4]; } H, L;
#pragma unroll
        for (int q = 0; q < 4; ++q) {
            const int k = 32 * s + 8 * g + 2 * q;
            split2(Wh[k * 64 + 16 * w + cidx], Wh[(k + 1) * 64 + 16 * w + cidx], H.u[q], L.u[q]);
        }
        WhH[s] = H.s8; WhL[s] = L.s8;
    }
    {
        union { short8 s8; unsigned u[4]; } H, L;
#pragma unroll
        for (int q = 0; q < 4; ++q) {
            const int k = 8 * g + 2 * q;
            split2(Wu[k * 64 + 16 * w + cidx], Wu[(k + 1) * 64 + 16 * w + cidx], H.u[q], L.u[q]);
        }
        WuH = H.s8; WuL = L.s8;
    }
    const f32x4 bu4 = *(const f32x4*)(bu + 16 * w + 4 * g);
    const f32x4 bh4 = *(const f32x4*)(bh + 16 * w + 4 * g);

    const char* eb = (const char*)ein_;
    const unsigned colb = 32u * w + 8u * g;
    const int S = gridDim.x;

    // staging shares + fragment-plane offsets
    const int side = w >> 1;
    const int sub  = w & 1;
    const unsigned fo = (unsigned)g * 256u + (unsigned)cidx * 16u;  // frag slot
    const unsigned o0 = 512u * (g & 1) + 16u * cidx;                // fp32 x-frag
    const unsigned rg = (unsigned)(g >> 1) * 1024u;

    // ---- prologue: stage tiles t and t+S; wave0 loads cont(t) ----
    int t = blockIdx.x;
    {
        const int2 cA = *(const int2*)(child + 2 * (t * 16 + cidx));
        int t1 = (t + S < ntiles) ? t + S : t;
        const int2 cB = *(const int2*)(child + 2 * (t1 * 16 + cidx));
        if (LEAF) {
            gld16(eb + (size_t)(side ? cA.y : cA.x) * 128 + sub * 64 + g * 16,
                  lds + 0 * STG + (side * 2 + sub) * 1024);
            gld16(eb + (size_t)(side ? cB.y : cB.x) * 128 + sub * 64 + g * 16,
                  lds + 1 * STG + (side * 2 + sub) * 1024);
        } else {
            const char* sbA = eb + (size_t)(side ? cA.y : cA.x) * 256 + sub * 64 + g * 16;
            const char* sbB = eb + (size_t)(side ? cB.y : cB.x) * 256 + sub * 64 + g * 16;
            gld16(sbA,       lds + 0 * STG + (side * 4 + sub * 2 + 0) * 1024);
            gld16(sbA + 128, lds + 0 * STG + (side * 4 + sub * 2 + 1) * 1024);
            gld16(sbB,       lds + 1 * STG + (side * 4 + sub * 2 + 0) * 1024);
            gld16(sbB + 128, lds + 1 * STG + (side * 4 + sub * 2 + 1) * 1024);
        }
    }
    f32x4 c0, c1;
    if (w == 0) {
        const f32x4* pc = (const f32x4*)(cont + (size_t)(t * 16 + cidx) * 32 + 8 * g);
        c0 = pc[0]; c1 = pc[1];
    }
    __syncthreads();   // prologue: full drain (staged buf0/buf1 + c0 complete)

    // prologue split-jobs: frag planes for tile 0
    if (w == 0) {
        short8 AH, AL;
        split8(c0, c1, AH, AL);
        *(short8*)(fpl + fo)        = AH;
        *(short8*)(fpl + 1024 + fo) = AL;
    } else if (LEAF && w <= 2) {
        const char* xb = lds + 0 * STG + (w - 1) * 2048;
        const f32x4 a = *(const f32x4*)(xb + rg + o0);
        const f32x4 b = *(const f32x4*)(xb + rg + o0 + 256);
        short8 AH, AL;
        split8(a, b, AH, AL);
        *(short8*)(fpl + w * 2048 + fo)        = AH;
        *(short8*)(fpl + w * 2048 + 1024 + fo) = AL;
    }
    __syncthreads();

    for (int k = 0; t < ntiles; t += S, ++k) {
        const int pb = k & 1;
        char* ub = upl0 + pb * (NPL * 2048);

        // prefetch: child idx for the staging tile, wave0 loads cont(t+S)
        int ts = LEAF ? (t + 2 * S) : (t + S);
        if (ts >= ntiles) ts = t;
        const int2 chN = *(const int2*)(child + 2 * (ts * 16 + cidx));
        int tn = (t + S < ntiles) ? t + S : t;
        if (w == 0) {
            const f32x4* pc = (const f32x4*)(cont + (size_t)(tn * 16 + cidx) * 32 + 8 * g);
            c0 = pc[0]; c1 = pc[1];
        }

        // ---- phase 1: u-GEMMs from frag planes; relu+split into u planes[pb] ----
        {
            const short8 aH = *(const short8*)(fpl + fo);
            const short8 aL = *(const short8*)(fpl + 1024 + fo);
            f32x4 ua = bu4;
            ua = MFMA16(WuH, aH, ua);
            ua = MFMA16(WuL, aH, ua);
            ua = MFMA16(WuH, aL, ua);
            const unsigned off = swz(cidx, colb);
            unsigned h0, l0, h1, l1;
            split2(fmaxf(ua[0], 0.f), fmaxf(ua[1], 0.f), h0, l0);
            split2(fmaxf(ua[2], 0.f), fmaxf(ua[3], 0.f), h1, l1);
            *(uint2*)(ub + (NPL - 2) * 2048 + off) = uint2{h0, h1};
            *(uint2*)(ub + (NPL - 1) * 2048 + off) = uint2{l0, l1};
            if (LEAF) {
#pragma unroll
                for (int sd = 0; sd < 2; ++sd) {
                    const short8 xH = *(const short8*)(fpl + (1 + sd) * 2048 + fo);
                    const short8 xL = *(const short8*)(fpl + (1 + sd) * 2048 + 1024 + fo);
                    f32x4 ux = bu4;
                    ux = MFMA16(WuH, xH, ux);
                    ux = MFMA16(WuL, xH, ux);
                    ux = MFMA16(WuH, xL, ux);
                    split2(fmaxf(ux[0], 0.f), fmaxf(ux[1], 0.f), h0, l0);
                    split2(fmaxf(ux[2], 0.f), fmaxf(ux[3], 0.f), h1, l1);
                    *(uint2*)(ub + (2 * sd + 0) * 2048 + off) = uint2{h0, h1};
                    *(uint2*)(ub + (2 * sd + 1) * 2048 + off) = uint2{l0, l1};
                }
            }
        }
        barrier_nv();   // A: u planes visible; staging stays in flight

        // ---- phase 2 ----
        // re-stage (leaf: -> buf[pb]; mid: -> buf[pb^1]); awaited NEXT iteration
        if (LEAF) {
            gld16(eb + (size_t)(side ? chN.y : chN.x) * 128 + sub * 64 + g * 16,
                  lds + pb * STG + (side * 2 + sub) * 1024);
        } else {
            const char* sN = eb + (size_t)(side ? chN.y : chN.x) * 256 + sub * 64 + g * 16;
            gld16(sN,       lds + (pb ^ 1) * STG + (side * 4 + sub * 2 + 0) * 1024);
            gld16(sN + 128, lds + (pb ^ 1) * STG + (side * 4 + sub * 2 + 1) * 1024);
        }

        f32x4 acc0 = bh4;
        f32x4 acc1 = {0.f, 0.f, 0.f, 0.f};
        if (LEAF) {
#pragma unroll
            for (int q = 0; q < 3; ++q) {
#pragma unroll
                for (int s = 0; s < 2; ++s) {
                    const short8 aH = *(const short8*)(ub + (2 * q + 0) * 2048 + swz(cidx, 64 * s + 16 * g));
                    const short8 aL = *(const short8*)(ub + (2 * q + 1) * 2048 + swz(cidx, 64 * s + 16 * g));
                    const int Sl = 2 * q + s;
                    f32x4 &acc = s ? acc1 : acc0;
                    acc = MFMA16(WhH[Sl], aH, acc);
                    acc = MFMA16(WhL[Sl], aH, acc);
                    acc = MFMA16(WhH[Sl], aL, acc);
                }
            }
        } else {
            // staged-fragment MFMAs: await last iteration's 2 gld16s (keep
            // this iteration's 2 newest in flight)
            VM_WAIT(2);
            const char* hb = lds + pb * STG;
#pragma unroll
            for (int sd = 0; sd < 2; ++sd) {
#pragma unroll
                for (int s = 0; s < 2; ++s) {
                    const short8 aH = *(const short8*)(hb + (sd * 4 + s * 2 + 0) * 1024 + 16 * lane);
                    const short8 aL = *(const short8*)(hb + (sd * 4 + s * 2 + 1) * 1024 + 16 * lane);
                    const int Sl = 2 * sd + s;
                    f32x4 &acc = sd ? acc1 : acc0;
                    acc = MFMA16(WhH[Sl], aH, acc);
                    acc = MFMA16(WhL[Sl], aH, acc);
                    acc = MFMA16(WhH[Sl], aL, acc);
                }
            }
#pragma unroll
            for (int s = 0; s < 2; ++s) {
                const short8 aH = *(const short8*)(ub + 0 * 2048 + swz(cidx, 64 * s + 16 * g));
                const short8 aL = *(const short8*)(ub + 1 * 2048 + swz(cidx, 64 * s + 16 * g));
                const int Sl = 4 + s;
                f32x4 &acc = s ? acc1 : acc0;
                acc = MFMA16(WhH[Sl], aH, acc);
                acc = MFMA16(WhL[Sl], aH, acc);
                acc = MFMA16(WhH[Sl], aL, acc);
            }
        }

        // split-jobs: frag planes for tile k+1 (consume staged x-rows at leaf)
        if (LEAF) VM_WAIT(1);   // await last iteration's gld16; keep this one's
        if (w == 0) {
            short8 AH, AL;
            split8(c0, c1, AH, AL);
            *(short8*)(fpl + fo)        = AH;
            *(short8*)(fpl + 1024 + fo) = AL;
        } else if (LEAF && w <= 2) {
            const char* xb = lds + (pb ^ 1) * STG + (w - 1) * 2048;  // tile k+1's x
            const f32x4 a = *(const f32x4*)(xb + rg + o0);
            const f32x4 b = *(const f32x4*)(xb + rg + o0 + 256);
            short8 AH, AL;
            split8(a, b, AH, AL);
            *(short8*)(fpl + w * 2048 + fo)        = AH;
            *(short8*)(fpl + w * 2048 + 1024 + fo) = AL;
        }

        // ---- store: lane holds out[row=cidx][cols 16w+4g .. +3] ----
        if (FINAL) {
            float* out = (float*)eout_;
            f32x4 v;
#pragma unroll
            for (int i = 0; i < 4; ++i) v[i] = fmaxf(acc0[i] + acc1[i], 0.f);
            *(f32x4*)(out + (size_t)(t * 16 + cidx) * 64 + 16 * w + 4 * g) = v;
        } else {
            char* out = (char*)eout_;
            const size_t rb = (size_t)(t * 16 + cidx) * 256;
            unsigned h0, l0, h1, l1;
            split2(fmaxf(acc0[0] + acc1[0], 0.f), fmaxf(acc0[1] + acc1[1], 0.f), h0, l0);
            split2(fmaxf(acc0[2] + acc1[2], 0.f), fmaxf(acc0[3] + acc1[3], 0.f), h1, l1);
            *(uint2*)(out + rb + colb)       = uint2{h0, h1};
            *(uint2*)(out + rb + 128 + colb) = uint2{l0, l1};
        }
        barrier_nv();   // B: frag planes visible; staging stays in flight
    }
}

extern "C" void kernel_launch(void* const* d_in, const int* in_sizes, int n_in,
                              void* d_out, int out_size, void* d_ws, size_t ws_size,
                              hipStream_t stream) {
    // inputs: contents0..8 = d_in[0..8], children0..7 = d_in[9..16],
    //         Wu = d_in[17], bu = d_in[18], Wh = d_in[19], bh = d_in[20]
    const float* Wu = (const float*)d_in[17];
    const float* bu = (const float*)d_in[18];
    const float* Wh = (const float*)d_in[19];
    const float* bh = (const float*)d_in[20];

    // emb_j stored as bf16 hi/lo planes, 256B/row
    void* bufA = d_ws;                               // emb7/5/3/1
    void* bufB = (char*)d_ws + (size_t)268435456;    // emb6/4/2

    const void* ein = d_in[8];  // contents8 (fp32) for the fused leaf level
    for (int j = 7; j >= 0; --j) {
        const int n      = in_sizes[j] / 32;
        const int ntiles = n / 16;
        void* eout = (j == 0) ? d_out : ((j & 1) ? bufA : bufB);
        int blocks = ntiles < 4096 ? ntiles : 4096;
        const float* cont  = (const float*)d_in[j];
        const int*   child = (const int*)d_in[9 + j];
        if (j == 7)
            grnn_mfma<true,  false><<<blocks, 256, 0, stream>>>(cont, child, ein, Wu, bu, Wh, bh, eout, ntiles);
        else if (j == 0)
            grnn_mfma<false, true ><<<blocks, 256, 0, stream>>>(cont, child, ein, Wu, bu, Wh, bh, eout, ntiles);
        else
            grnn_mfma<false, false><<<blocks, 256, 0, stream>>>(cont, child, ein, Wu, bu, Wh, bh, eout, ntiles);
        ein = eout;
    }
}

// Round 12
// 523.766 us; speedup vs baseline: 1.7607x; 1.0002x over previous
//
#include <hip/hip_runtime.h>
#include <hip/hip_bf16.h>

typedef __attribute__((ext_vector_type(8))) short  short8;
typedef __attribute__((ext_vector_type(4))) float  f32x4;

#define MFMA16(A,B,C) __builtin_amdgcn_mfma_f32_16x16x32_bf16((A),(B),(C),0,0,0)

// LDS-visibility barrier WITHOUT the vmcnt drain: staged global_load_lds ops
// stay in flight across it. (T3/T4: never drain vmcnt to 0 in the main loop.)
__device__ __forceinline__ void barrier_nv() {
    __builtin_amdgcn_sched_barrier(0);
    asm volatile("s_waitcnt lgkmcnt(0)" ::: "memory");
    __builtin_amdgcn_s_barrier();
    __builtin_amdgcn_sched_barrier(0);
}
// counted vmem wait: proves all but the N newest vmem ops complete.
#define VM_WAIT(N) do { asm volatile("s_waitcnt vmcnt(" #N ")" ::: "memory"); \
                        __builtin_amdgcn_sched_barrier(0); } while (0)

// ---- fp32 -> bf16 hi/lo split, pair-packed (cvt_pk path) ----
__device__ __forceinline__ void split2(float x0, float x1, unsigned &hp, unsigned &lp) {
    __hip_bfloat162 h = __float22bfloat162_rn(float2{x0, x1});
    union { __hip_bfloat162 b; unsigned u; } uh, ul;
    uh.b = h;
    float f0 = __bfloat162float(h.x);
    float f1 = __bfloat162float(h.y);
    ul.b = __float22bfloat162_rn(float2{x0 - f0, x1 - f1});
    hp = uh.u; lp = ul.u;
}

__device__ __forceinline__ void split8(const f32x4 a, const f32x4 b, short8 &h, short8 &l) {
    union { short8 s; unsigned u[4]; } H, L;
    split2(a[0], a[1], H.u[0], L.u[0]);
    split2(a[2], a[3], H.u[1], L.u[1]);
    split2(b[0], b[1], H.u[2], L.u[2]);
    split2(b[2], b[3], H.u[3], L.u[3]);
    h = H.s; l = L.s;
}

// XOR-swizzled byte offset inside a [16 rows][64 bf16] plane (row stride 128B).
__device__ __forceinline__ unsigned swz(unsigned row, unsigned colbyte) {
    return row * 128u + (colbyte ^ ((row & 7u) << 4));
}

// async global->LDS, 16B/lane. Global address is PER-LANE; LDS dest is the
// wave-uniform region base (HW writes base + lane*16).
__device__ __forceinline__ void gld16(const void* g, void* l) {
    __builtin_amdgcn_global_load_lds(
        (const __attribute__((address_space(1))) unsigned int*)g,
        (__attribute__((address_space(3))) unsigned int*)l, 16, 0, 0);
}

// Tree level, transposed-MFMA orientation (R11 schedule). LDS diet: u planes
// and frag planes are SINGLE-buffered (writer phase1(k)/phase2(k) and reader
// phase2(k)/phase1(k+1) are separated by barriers A/B — no overlap), only the
// gather staging buffers stay parity-double-buffered. Leaf 26.6KB -> 6 blk/CU,
// mid 22.5KB -> 7 blk/CU.
template<bool LEAF, bool FINAL>
__global__ __launch_bounds__(256, 4)
void grnn_mfma(const float* __restrict__ cont,   // ntiles*16 x 32 (fp32)
               const int*   __restrict__ child,  // ntiles*16 x 2
               const void*  __restrict__ ein_,   // emb_{j+1} hi/lo planes or contents8 fp32
               const float* __restrict__ Wu,     // 32 x 64
               const float* __restrict__ bu,     // 64
               const float* __restrict__ Wh,     // 192 x 64
               const float* __restrict__ bh,     // 64
               void*        __restrict__ eout_,  // hi/lo planes (fp32 if FINAL)
               int ntiles)
{
    constexpr int STG = LEAF ? 4096 : 8192;   // staged gather bytes per parity
    constexpr int NPL = LEAF ? 6 : 2;         // u planes (single-buffered)
    constexpr int NFP = LEAF ? 3 : 1;         // frag planes: cont[,xL,xR]
    __shared__ __align__(16) char lds[2 * STG + NPL * 2048 + NFP * 2048];
    char* ub  = lds + 2 * STG;                // u planes
    char* fpl = lds + 2 * STG + NPL * 2048;   // frag planes

    const int lane = threadIdx.x & 63;
    const int w    = threadIdx.x >> 6;
    const int cidx = lane & 15;
    const int g    = lane >> 4;

    // ---- weight fragments (hi/lo), transposed orientation ----
    short8 WhH[6], WhL[6], WuH, WuL;
#pragma unroll
    for (int s = 0; s < 6; ++s) {
        union { short8 s8; unsigned u[4]; } H, L;
#pragma unroll
        for (int q = 0; q < 4; ++q) {
            const int k = 32 * s + 8 * g + 2 * q;
            split2(Wh[k * 64 + 16 * w + cidx], Wh[(k + 1) * 64 + 16 * w + cidx], H.u[q], L.u[q]);
        }
        WhH[s] = H.s8; WhL[s] = L.s8;
    }
    {
        union { short8 s8; unsigned u[4]; } H, L;
#pragma unroll
        for (int q = 0; q < 4; ++q) {
            const int k = 8 * g + 2 * q;
            split2(Wu[k * 64 + 16 * w + cidx], Wu[(k + 1) * 64 + 16 * w + cidx], H.u[q], L.u[q]);
        }
        WuH = H.s8; WuL = L.s8;
    }
    const f32x4 bu4 = *(const f32x4*)(bu + 16 * w + 4 * g);
    const f32x4 bh4 = *(const f32x4*)(bh + 16 * w + 4 * g);

    const char* eb = (const char*)ein_;
    const unsigned colb = 32u * w + 8u * g;
    const int S = gridDim.x;

    // staging shares + fragment-plane offsets
    const int side = w >> 1;
    const int sub  = w & 1;
    const unsigned fo = (unsigned)g * 256u + (unsigned)cidx * 16u;  // frag slot
    const unsigned o0 = 512u * (g & 1) + 16u * cidx;                // fp32 x-frag
    const unsigned rg = (unsigned)(g >> 1) * 1024u;

    // ---- prologue: stage tiles t and t+S; wave0 loads cont(t) ----
    int t = blockIdx.x;
    {
        const int2 cA = *(const int2*)(child + 2 * (t * 16 + cidx));
        int t1 = (t + S < ntiles) ? t + S : t;
        const int2 cB = *(const int2*)(child + 2 * (t1 * 16 + cidx));
        if (LEAF) {
            gld16(eb + (size_t)(side ? cA.y : cA.x) * 128 + sub * 64 + g * 16,
                  lds + 0 * STG + (side * 2 + sub) * 1024);
            gld16(eb + (size_t)(side ? cB.y : cB.x) * 128 + sub * 64 + g * 16,
                  lds + 1 * STG + (side * 2 + sub) * 1024);
        } else {
            const char* sbA = eb + (size_t)(side ? cA.y : cA.x) * 256 + sub * 64 + g * 16;
            const char* sbB = eb + (size_t)(side ? cB.y : cB.x) * 256 + sub * 64 + g * 16;
            gld16(sbA,       lds + 0 * STG + (side * 4 + sub * 2 + 0) * 1024);
            gld16(sbA + 128, lds + 0 * STG + (side * 4 + sub * 2 + 1) * 1024);
            gld16(sbB,       lds + 1 * STG + (side * 4 + sub * 2 + 0) * 1024);
            gld16(sbB + 128, lds + 1 * STG + (side * 4 + sub * 2 + 1) * 1024);
        }
    }
    f32x4 c0, c1;
    if (w == 0) {
        const f32x4* pc = (const f32x4*)(cont + (size_t)(t * 16 + cidx) * 32 + 8 * g);
        c0 = pc[0]; c1 = pc[1];
    }
    __syncthreads();   // prologue: full drain (staged buf0/buf1 + c0 complete)

    // prologue split-jobs: frag planes for tile 0
    if (w == 0) {
        short8 AH, AL;
        split8(c0, c1, AH, AL);
        *(short8*)(fpl + fo)        = AH;
        *(short8*)(fpl + 1024 + fo) = AL;
    } else if (LEAF && w <= 2) {
        const char* xb = lds + 0 * STG + (w - 1) * 2048;
        const f32x4 a = *(const f32x4*)(xb + rg + o0);
        const f32x4 b = *(const f32x4*)(xb + rg + o0 + 256);
        short8 AH, AL;
        split8(a, b, AH, AL);
        *(short8*)(fpl + w * 2048 + fo)        = AH;
        *(short8*)(fpl + w * 2048 + 1024 + fo) = AL;
    }
    __syncthreads();

    for (int k = 0; t < ntiles; t += S, ++k) {
        const int pb = k & 1;

        // prefetch: child idx for the staging tile, wave0 loads cont(t+S)
        int ts = LEAF ? (t + 2 * S) : (t + S);
        if (ts >= ntiles) ts = t;
        const int2 chN = *(const int2*)(child + 2 * (ts * 16 + cidx));
        int tn = (t + S < ntiles) ? t + S : t;
        if (w == 0) {
            const f32x4* pc = (const f32x4*)(cont + (size_t)(tn * 16 + cidx) * 32 + 8 * g);
            c0 = pc[0]; c1 = pc[1];
        }

        // ---- phase 1: u-GEMMs from frag planes; relu+split into u planes ----
        {
            const short8 aH = *(const short8*)(fpl + fo);
            const short8 aL = *(const short8*)(fpl + 1024 + fo);
            f32x4 ua = bu4;
            ua = MFMA16(WuH, aH, ua);
            ua = MFMA16(WuL, aH, ua);
            ua = MFMA16(WuH, aL, ua);
            const unsigned off = swz(cidx, colb);
            unsigned h0, l0, h1, l1;
            split2(fmaxf(ua[0], 0.f), fmaxf(ua[1], 0.f), h0, l0);
            split2(fmaxf(ua[2], 0.f), fmaxf(ua[3], 0.f), h1, l1);
            *(uint2*)(ub + (NPL - 2) * 2048 + off) = uint2{h0, h1};
            *(uint2*)(ub + (NPL - 1) * 2048 + off) = uint2{l0, l1};
            if (LEAF) {
#pragma unroll
                for (int sd = 0; sd < 2; ++sd) {
                    const short8 xH = *(const short8*)(fpl + (1 + sd) * 2048 + fo);
                    const short8 xL = *(const short8*)(fpl + (1 + sd) * 2048 + 1024 + fo);
                    f32x4 ux = bu4;
                    ux = MFMA16(WuH, xH, ux);
                    ux = MFMA16(WuL, xH, ux);
                    ux = MFMA16(WuH, xL, ux);
                    split2(fmaxf(ux[0], 0.f), fmaxf(ux[1], 0.f), h0, l0);
                    split2(fmaxf(ux[2], 0.f), fmaxf(ux[3], 0.f), h1, l1);
                    *(uint2*)(ub + (2 * sd + 0) * 2048 + off) = uint2{h0, h1};
                    *(uint2*)(ub + (2 * sd + 1) * 2048 + off) = uint2{l0, l1};
                }
            }
        }
        barrier_nv();   // A: u planes visible; staging stays in flight

        // ---- phase 2 ----
        // re-stage (leaf: -> buf[pb]; mid: -> buf[pb^1]); awaited NEXT iteration
        if (LEAF) {
            gld16(eb + (size_t)(side ? chN.y : chN.x) * 128 + sub * 64 + g * 16,
                  lds + pb * STG + (side * 2 + sub) * 1024);
        } else {
            const char* sN = eb + (size_t)(side ? chN.y : chN.x) * 256 + sub * 64 + g * 16;
            gld16(sN,       lds + (pb ^ 1) * STG + (side * 4 + sub * 2 + 0) * 1024);
            gld16(sN + 128, lds + (pb ^ 1) * STG + (side * 4 + sub * 2 + 1) * 1024);
        }

        f32x4 acc0 = bh4;
        f32x4 acc1 = {0.f, 0.f, 0.f, 0.f};
        if (LEAF) {
#pragma unroll
            for (int q = 0; q < 3; ++q) {
#pragma unroll
                for (int s = 0; s < 2; ++s) {
                    const short8 aH = *(const short8*)(ub + (2 * q + 0) * 2048 + swz(cidx, 64 * s + 16 * g));
                    const short8 aL = *(const short8*)(ub + (2 * q + 1) * 2048 + swz(cidx, 64 * s + 16 * g));
                    const int Sl = 2 * q + s;
                    f32x4 &acc = s ? acc1 : acc0;
                    acc = MFMA16(WhH[Sl], aH, acc);
                    acc = MFMA16(WhL[Sl], aH, acc);
                    acc = MFMA16(WhH[Sl], aL, acc);
                }
            }
        } else {
            // staged-fragment MFMAs: await last iteration's 2 gld16s (keep
            // this iteration's 2 newest in flight)
            VM_WAIT(2);
            const char* hb = lds + pb * STG;
#pragma unroll
            for (int sd = 0; sd < 2; ++sd) {
#pragma unroll
                for (int s = 0; s < 2; ++s) {
                    const short8 aH = *(const short8*)(hb + (sd * 4 + s * 2 + 0) * 1024 + 16 * lane);
                    const short8 aL = *(const short8*)(hb + (sd * 4 + s * 2 + 1) * 1024 + 16 * lane);
                    const int Sl = 2 * sd + s;
                    f32x4 &acc = sd ? acc1 : acc0;
                    acc = MFMA16(WhH[Sl], aH, acc);
                    acc = MFMA16(WhL[Sl], aH, acc);
                    acc = MFMA16(WhH[Sl], aL, acc);
                }
            }
#pragma unroll
            for (int s = 0; s < 2; ++s) {
                const short8 aH = *(const short8*)(ub + 0 * 2048 + swz(cidx, 64 * s + 16 * g));
                const short8 aL = *(const short8*)(ub + 1 * 2048 + swz(cidx, 64 * s + 16 * g));
                const int Sl = 4 + s;
                f32x4 &acc = s ? acc1 : acc0;
                acc = MFMA16(WhH[Sl], aH, acc);
                acc = MFMA16(WhL[Sl], aH, acc);
                acc = MFMA16(WhH[Sl], aL, acc);
            }
        }

        // split-jobs: frag planes for tile k+1 (consume staged x-rows at leaf)
        if (LEAF) VM_WAIT(1);   // await last iteration's gld16; keep this one's
        if (w == 0) {
            short8 AH, AL;
            split8(c0, c1, AH, AL);
            *(short8*)(fpl + fo)        = AH;
            *(short8*)(fpl + 1024 + fo) = AL;
        } else if (LEAF && w <= 2) {
            const char* xb = lds + (pb ^ 1) * STG + (w - 1) * 2048;  // tile k+1's x
            const f32x4 a = *(const f32x4*)(xb + rg + o0);
            const f32x4 b = *(const f32x4*)(xb + rg + o0 + 256);
            short8 AH, AL;
            split8(a, b, AH, AL);
            *(short8*)(fpl + w * 2048 + fo)        = AH;
            *(short8*)(fpl + w * 2048 + 1024 + fo) = AL;
        }

        // ---- store: lane holds out[row=cidx][cols 16w+4g .. +3] ----
        if (FINAL) {
            float* out = (float*)eout_;
            f32x4 v;
#pragma unroll
            for (int i = 0; i < 4; ++i) v[i] = fmaxf(acc0[i] + acc1[i], 0.f);
            *(f32x4*)(out + (size_t)(t * 16 + cidx) * 64 + 16 * w + 4 * g) = v;
        } else {
            char* out = (char*)eout_;
            const size_t rb = (size_t)(t * 16 + cidx) * 256;
            unsigned h0, l0, h1, l1;
            split2(fmaxf(acc0[0] + acc1[0], 0.f), fmaxf(acc0[1] + acc1[1], 0.f), h0, l0);
            split2(fmaxf(acc0[2] + acc1[2], 0.f), fmaxf(acc0[3] + acc1[3], 0.f), h1, l1);
            *(uint2*)(out + rb + colb)       = uint2{h0, h1};
            *(uint2*)(out + rb + 128 + colb) = uint2{l0, l1};
        }
        barrier_nv();   // B: frag planes visible; staging stays in flight
    }
}

extern "C" void kernel_launch(void* const* d_in, const int* in_sizes, int n_in,
                              void* d_out, int out_size, void* d_ws, size_t ws_size,
                              hipStream_t stream) {
    // inputs: contents0..8 = d_in[0..8], children0..7 = d_in[9..16],
    //         Wu = d_in[17], bu = d_in[18], Wh = d_in[19], bh = d_in[20]
    const float* Wu = (const float*)d_in[17];
    const float* bu = (const float*)d_in[18];
    const float* Wh = (const float*)d_in[19];
    const float* bh = (const float*)d_in[20];

    // emb_j stored as bf16 hi/lo planes, 256B/row
    void* bufA = d_ws;                               // emb7/5/3/1
    void* bufB = (char*)d_ws + (size_t)268435456;    // emb6/4/2

    const void* ein = d_in[8];  // contents8 (fp32) for the fused leaf level
    for (int j = 7; j >= 0; --j) {
        const int n      = in_sizes[j] / 32;
        const int ntiles = n / 16;
        void* eout = (j == 0) ? d_out : ((j & 1) ? bufA : bufB);
        int blocks = ntiles < 4096 ? ntiles : 4096;
        const float* cont  = (const float*)d_in[j];
        const int*   child = (const int*)d_in[9 + j];
        if (j == 7)
            grnn_mfma<true,  false><<<blocks, 256, 0, stream>>>(cont, child, ein, Wu, bu, Wh, bh, eout, ntiles);
        else if (j == 0)
            grnn_mfma<false, true ><<<blocks, 256, 0, stream>>>(cont, child, ein, Wu, bu, Wh, bh, eout, ntiles);
        else
            grnn_mfma<false, false><<<blocks, 256, 0, stream>>>(cont, child, ein, Wu, bu, Wh, bh, eout, ntiles);
        ein = eout;
    }
}

// Round 13
// 510.654 us; speedup vs baseline: 1.8059x; 1.0257x over previous
//
#include <hip/hip_runtime.h>
#include <hip/hip_bf16.h>

typedef __attribute__((ext_vector_type(8))) short  short8;
typedef __attribute__((ext_vector_type(4))) float  f32x4;

#define MFMA16(A,B,C) __builtin_amdgcn_mfma_f32_16x16x32_bf16((A),(B),(C),0,0,0)

// LDS-visibility barrier WITHOUT the vmcnt drain (T3/T4).
__device__ __forceinline__ void barrier_nv() {
    __builtin_amdgcn_sched_barrier(0);
    asm volatile("s_waitcnt lgkmcnt(0)" ::: "memory");
    __builtin_amdgcn_s_barrier();
    __builtin_amdgcn_sched_barrier(0);
}
// counted vmem wait (vmcnt retires in issue order: waits the oldest ops)
#define VM_WAIT(N) do { asm volatile("s_waitcnt vmcnt(" #N ")" ::: "memory"); \
                        __builtin_amdgcn_sched_barrier(0); } while (0)

// ---- fp32 -> bf16 hi/lo split, pair-packed (cvt_pk path) ----
__device__ __forceinline__ void split2(float x0, float x1, unsigned &hp, unsigned &lp) {
    __hip_bfloat162 h = __float22bfloat162_rn(float2{x0, x1});
    union { __hip_bfloat162 b; unsigned u; } uh, ul;
    uh.b = h;
    float f0 = __bfloat162float(h.x);
    float f1 = __bfloat162float(h.y);
    ul.b = __float22bfloat162_rn(float2{x0 - f0, x1 - f1});
    hp = uh.u; lp = ul.u;
}

__device__ __forceinline__ void split8(const f32x4 a, const f32x4 b, short8 &h, short8 &l) {
    union { short8 s; unsigned u[4]; } H, L;
    split2(a[0], a[1], H.u[0], L.u[0]);
    split2(a[2], a[3], H.u[1], L.u[1]);
    split2(b[0], b[1], H.u[2], L.u[2]);
    split2(b[2], b[3], H.u[3], L.u[3]);
    h = H.s; l = L.s;
}

// XOR-swizzled byte offset inside a [16 rows][64 bf16] plane (row stride 128B).
__device__ __forceinline__ unsigned swz(unsigned row, unsigned colbyte) {
    return row * 128u + (colbyte ^ ((row & 7u) << 4));
}

// async global->LDS, 16B/lane (per-lane global addr, lane-linear LDS dest).
__device__ __forceinline__ void gld16(const void* g, void* l) {
    __builtin_amdgcn_global_load_lds(
        (const __attribute__((address_space(1))) unsigned int*)g,
        (__attribute__((address_space(3))) unsigned int*)l, 16, 0, 0);
}

// Tree level, transposed-MFMA orientation. TWO tiles (a pair) per iteration:
// same 2-barrier skeleton, 2x work per barrier, 4 independent MFMA chains.
// Race-proof staging: leaf wave w stages exactly the regions its own split-job
// reads (w = tile*2 + side); child idx regs pipelined 1 iter so staging needs
// no fresh load; VM_WAIT(4) (leaf, pre-split-jobs) / vmcnt(0)-before-barrier-A
// (mid, cross-wave consumers) guarantee staged data landed.
template<bool LEAF, bool FINAL>
__global__ __launch_bounds__(256, 3)
void grnn_mfma(const float* __restrict__ cont,   // rows x 32 (fp32)
               const int*   __restrict__ child,  // rows x 2
               const void*  __restrict__ ein_,   // emb hi/lo planes or contents8 fp32
               const float* __restrict__ Wu,     // 32 x 64
               const float* __restrict__ bu,     // 64
               const float* __restrict__ Wh,     // 192 x 64
               const float* __restrict__ bh,     // 64
               void*        __restrict__ eout_,  // hi/lo planes (fp32 if FINAL)
               int npairs)                        // ntiles/2
{
    constexpr int TS  = LEAF ? 4096 : 8192;   // staging bytes per tile
    constexpr int STG = 2 * TS;               // per parity (one pair)
    constexpr int NPL = LEAF ? 6 : 2;
    constexpr int NFP = LEAF ? 3 : 1;
    constexpr int UST = NPL * 2048;           // u-plane stride per tile
    constexpr int FST = NFP * 2048;           // frag-plane stride per tile
    __shared__ __align__(16) char lds[2 * STG + 2 * UST + 2 * FST];
    char* ub  = lds + 2 * STG;
    char* fpl = ub + 2 * UST;

    const int lane = threadIdx.x & 63;
    const int w    = threadIdx.x >> 6;
    const int cidx = lane & 15;
    const int g    = lane >> 4;

    // ---- weight fragments (hi/lo), transposed orientation ----
    short8 WhH[6], WhL[6], WuH, WuL;
#pragma unroll
    for (int s = 0; s < 6; ++s) {
        union { short8 s8; unsigned u[4]; } H, L;
#pragma unroll
        for (int q = 0; q < 4; ++q) {
            const int k = 32 * s + 8 * g + 2 * q;
            split2(Wh[k * 64 + 16 * w + cidx], Wh[(k + 1) * 64 + 16 * w + cidx], H.u[q], L.u[q]);
        }
        WhH[s] = H.s8; WhL[s] = L.s8;
    }
    {
        union { short8 s8; unsigned u[4]; } H, L;
#pragma unroll
        for (int q = 0; q < 4; ++q) {
            const int k = 8 * g + 2 * q;
            split2(Wu[k * 64 + 16 * w + cidx], Wu[(k + 1) * 64 + 16 * w + cidx], H.u[q], L.u[q]);
        }
        WuH = H.s8; WuL = L.s8;
    }
    const f32x4 bu4 = *(const f32x4*)(bu + 16 * w + 4 * g);
    const f32x4 bh4 = *(const f32x4*)(bh + 16 * w + 4 * g);

    const char* eb = (const char*)ein_;
    const unsigned colb = 32u * w + 8u * g;
    const int S = gridDim.x;

    const int ltile = w >> 1, lside = w & 1;   // leaf staging share (self-read)
    const int mside = w >> 1, msub  = w & 1;   // mid staging share
    const unsigned fo = (unsigned)g * 256u + (unsigned)cidx * 16u;
    const unsigned o0 = 512u * (g & 1) + 16u * cidx;
    const unsigned rg = (unsigned)(g >> 1) * 1024u;

    int p = blockIdx.x;
    const int p1 = (p + S < npairs) ? p + S : p;
    const int ps0 = LEAF ? ((p + 2 * S < npairs) ? p + 2 * S : p) : p1;

    int2 sA, sB;   // child rows of the pair staged at the next staging point

    // ---- prologue ----
    {
        const int2 cA = *(const int2*)(child + 2 * (2 * p * 16 + cidx));
        const int2 cB = *(const int2*)(child + 2 * ((2 * p + 1) * 16 + cidx));
        if (LEAF) {
            { int2 ch = ltile ? cB : cA; const int c = lside ? ch.y : ch.x;
              char* d = lds + 0 * STG + ltile * TS + lside * 2048;
              gld16(eb + (size_t)c * 128 +      g * 16, d);
              gld16(eb + (size_t)c * 128 + 64 + g * 16, d + 1024); }
            const int2 dA = *(const int2*)(child + 2 * (2 * p1 * 16 + cidx));
            const int2 dB = *(const int2*)(child + 2 * ((2 * p1 + 1) * 16 + cidx));
            { int2 ch = ltile ? dB : dA; const int c = lside ? ch.y : ch.x;
              char* d = lds + 1 * STG + ltile * TS + lside * 2048;
              gld16(eb + (size_t)c * 128 +      g * 16, d);
              gld16(eb + (size_t)c * 128 + 64 + g * 16, d + 1024); }
        } else {
#pragma unroll
            for (int tt = 0; tt < 2; ++tt) {
                int2 ch = tt ? cB : cA; const int c = mside ? ch.y : ch.x;
                const char* sN = eb + (size_t)c * 256 + msub * 64 + g * 16;
                char* d = lds + 0 * STG + tt * TS + (mside * 4 + msub * 2) * 1024;
                gld16(sN,       d);
                gld16(sN + 128, d + 1024);
            }
        }
        sA = *(const int2*)(child + 2 * (2 * ps0 * 16 + cidx));
        sB = *(const int2*)(child + 2 * ((2 * ps0 + 1) * 16 + cidx));
    }
    f32x4 c0, c1;
    if (w == 0) {
        const f32x4* pc = (const f32x4*)(cont + (size_t)(2 * p * 16 + cidx) * 32 + 8 * g);
        c0 = pc[0]; c1 = pc[1];
    } else if (w == (LEAF ? 2 : 1)) {
        const f32x4* pc = (const f32x4*)(cont + (size_t)((2 * p + 1) * 16 + cidx) * 32 + 8 * g);
        c0 = pc[0]; c1 = pc[1];
    }
    __syncthreads();   // full drain: prologue staging + regs complete

    // prologue frag jobs for pair p
    if (LEAF) {
        const int tt = w >> 1;
        if ((w & 1) == 0) {        // w0/w2: cont + xL of tile tt
            short8 AH, AL;
            split8(c0, c1, AH, AL);
            *(short8*)(fpl + tt * FST + fo)        = AH;
            *(short8*)(fpl + tt * FST + 1024 + fo) = AL;
            const char* xb = lds + 0 * STG + tt * TS;          // side 0
            const f32x4 a = *(const f32x4*)(xb + rg + o0);
            const f32x4 b = *(const f32x4*)(xb + rg + o0 + 256);
            split8(a, b, AH, AL);
            *(short8*)(fpl + tt * FST + 2048 + fo) = AH;
            *(short8*)(fpl + tt * FST + 3072 + fo) = AL;
        } else {                    // w1/w3: xR of tile tt
            const char* xb = lds + 0 * STG + tt * TS + 2048;   // side 1
            const f32x4 a = *(const f32x4*)(xb + rg + o0);
            const f32x4 b = *(const f32x4*)(xb + rg + o0 + 256);
            short8 AH, AL;
            split8(a, b, AH, AL);
            *(short8*)(fpl + tt * FST + 4096 + fo) = AH;
            *(short8*)(fpl + tt * FST + 5120 + fo) = AL;
        }
    } else if (w <= 1) {
        short8 AH, AL;
        split8(c0, c1, AH, AL);
        *(short8*)(fpl + w * FST + fo)        = AH;
        *(short8*)(fpl + w * FST + 1024 + fo) = AL;
    }
    __syncthreads();

    for (int k = 0; p < npairs; p += S, ++k) {
        const int pb = k & 1;
        const int pf = (p + S < npairs) ? p + S : p;
        const int pn = LEAF ? ((p + 3 * S < npairs) ? p + 3 * S : p)
                            : ((p + 2 * S < npairs) ? p + 2 * S : p);

        // ---- phase 1: u-GEMMs for both tiles of pair p ----
#pragma unroll
        for (int tt = 0; tt < 2; ++tt) {
            const short8 aH = *(const short8*)(fpl + tt * FST + fo);
            const short8 aL = *(const short8*)(fpl + tt * FST + 1024 + fo);
            f32x4 ua = bu4;
            ua = MFMA16(WuH, aH, ua);
            ua = MFMA16(WuL, aH, ua);
            ua = MFMA16(WuH, aL, ua);
            const unsigned off = swz(cidx, colb);
            unsigned h0, l0, h1, l1;
            split2(fmaxf(ua[0], 0.f), fmaxf(ua[1], 0.f), h0, l0);
            split2(fmaxf(ua[2], 0.f), fmaxf(ua[3], 0.f), h1, l1);
            *(uint2*)(ub + tt * UST + (NPL - 2) * 2048 + off) = uint2{h0, h1};
            *(uint2*)(ub + tt * UST + (NPL - 1) * 2048 + off) = uint2{l0, l1};
            if (LEAF) {
#pragma unroll
                for (int sd = 0; sd < 2; ++sd) {
                    const short8 xH = *(const short8*)(fpl + tt * FST + (1 + sd) * 2048 + fo);
                    const short8 xL = *(const short8*)(fpl + tt * FST + (1 + sd) * 2048 + 1024 + fo);
                    f32x4 ux = bu4;
                    ux = MFMA16(WuH, xH, ux);
                    ux = MFMA16(WuL, xH, ux);
                    ux = MFMA16(WuH, xL, ux);
                    split2(fmaxf(ux[0], 0.f), fmaxf(ux[1], 0.f), h0, l0);
                    split2(fmaxf(ux[2], 0.f), fmaxf(ux[3], 0.f), h1, l1);
                    *(uint2*)(ub + tt * UST + (2 * sd + 0) * 2048 + off) = uint2{h0, h1};
                    *(uint2*)(ub + tt * UST + (2 * sd + 1) * 2048 + off) = uint2{l0, l1};
                }
            }
        }
        if (!LEAF) VM_WAIT(0);   // own staging drained pre-A -> visible to ALL waves post-A
        barrier_nv();            // A

        // ---- phase 2 ----
        // cont loads for pair pf (oldest this-iter vmem: drained by leaf VM_WAIT(4))
        if (w == 0) {
            const f32x4* pc = (const f32x4*)(cont + (size_t)(2 * pf * 16 + cidx) * 32 + 8 * g);
            c0 = pc[0]; c1 = pc[1];
        } else if (w == (LEAF ? 2 : 1)) {
            const f32x4* pc = (const f32x4*)(cont + (size_t)((2 * pf + 1) * 16 + cidx) * 32 + 8 * g);
            c0 = pc[0]; c1 = pc[1];
        }
        // stage next pair from pipelined child regs (no fresh dependent load)
        if (LEAF) {
            int2 ch = ltile ? sB : sA; const int c = lside ? ch.y : ch.x;
            char* d = lds + pb * STG + ltile * TS + lside * 2048;
            gld16(eb + (size_t)c * 128 +      g * 16, d);
            gld16(eb + (size_t)c * 128 + 64 + g * 16, d + 1024);
        } else {
#pragma unroll
            for (int tt = 0; tt < 2; ++tt) {
                int2 ch = tt ? sB : sA; const int c = mside ? ch.y : ch.x;
                const char* sN = eb + (size_t)c * 256 + msub * 64 + g * 16;
                char* d = lds + (pb ^ 1) * STG + tt * TS + (mside * 4 + msub * 2) * 1024;
                gld16(sN,       d);
                gld16(sN + 128, d + 1024);
            }
        }
        __builtin_amdgcn_sched_barrier(0);
        // child regs for the NEXT staging point (issued after staging: their use
        // next iter force-drains this iter's staging before split-jobs read it)
        int2 nA = *(const int2*)(child + 2 * (2 * pn * 16 + cidx));
        int2 nB = *(const int2*)(child + 2 * ((2 * pn + 1) * 16 + cidx));

        // h-GEMMs (4 independent accumulator chains)
        f32x4 acc[2][2];
        acc[0][0] = bh4; acc[0][1] = f32x4{0.f, 0.f, 0.f, 0.f};
        acc[1][0] = bh4; acc[1][1] = f32x4{0.f, 0.f, 0.f, 0.f};
        if (LEAF) {
#pragma unroll
            for (int tt = 0; tt < 2; ++tt)
#pragma unroll
            for (int q = 0; q < 3; ++q)
#pragma unroll
            for (int s = 0; s < 2; ++s) {
                const short8 aH = *(const short8*)(ub + tt * UST + (2 * q + 0) * 2048 + swz(cidx, 64 * s + 16 * g));
                const short8 aL = *(const short8*)(ub + tt * UST + (2 * q + 1) * 2048 + swz(cidx, 64 * s + 16 * g));
                const int Sl = 2 * q + s;
                acc[tt][s] = MFMA16(WhH[Sl], aH, acc[tt][s]);
                acc[tt][s] = MFMA16(WhL[Sl], aH, acc[tt][s]);
                acc[tt][s] = MFMA16(WhH[Sl], aL, acc[tt][s]);
            }
        } else {
#pragma unroll
            for (int tt = 0; tt < 2; ++tt) {
                const char* hb = lds + pb * STG + tt * TS;
#pragma unroll
                for (int sd = 0; sd < 2; ++sd)
#pragma unroll
                for (int s = 0; s < 2; ++s) {
                    const short8 aH = *(const short8*)(hb + (sd * 4 + s * 2 + 0) * 1024 + 16 * lane);
                    const short8 aL = *(const short8*)(hb + (sd * 4 + s * 2 + 1) * 1024 + 16 * lane);
                    const int Sl = 2 * sd + s;
                    acc[tt][sd] = MFMA16(WhH[Sl], aH, acc[tt][sd]);
                    acc[tt][sd] = MFMA16(WhL[Sl], aH, acc[tt][sd]);
                    acc[tt][sd] = MFMA16(WhH[Sl], aL, acc[tt][sd]);
                }
#pragma unroll
                for (int s = 0; s < 2; ++s) {
                    const short8 aH = *(const short8*)(ub + tt * UST + 0 * 2048 + swz(cidx, 64 * s + 16 * g));
                    const short8 aL = *(const short8*)(ub + tt * UST + 1 * 2048 + swz(cidx, 64 * s + 16 * g));
                    const int Sl = 4 + s;
                    acc[tt][s] = MFMA16(WhH[Sl], aH, acc[tt][s]);
                    acc[tt][s] = MFMA16(WhL[Sl], aH, acc[tt][s]);
                    acc[tt][s] = MFMA16(WhH[Sl], aL, acc[tt][s]);
                }
            }
        }

        // split-jobs for pair pf
        if (LEAF) {
            // drain all but the 4 newest (this iter's 2 staging + 2 child) ->
            // last-iter staging of buf[pb^1] provably landed; self-regions only.
            VM_WAIT(4);
            const char* xbase = lds + (pb ^ 1) * STG;
            const int tt = w >> 1;
            if ((w & 1) == 0) {        // w0/w2: cont + xL of tile tt
                short8 AH, AL;
                split8(c0, c1, AH, AL);
                *(short8*)(fpl + tt * FST + fo)        = AH;
                *(short8*)(fpl + tt * FST + 1024 + fo) = AL;
                const char* xb = xbase + tt * TS;
                const f32x4 a = *(const f32x4*)(xb + rg + o0);
                const f32x4 b = *(const f32x4*)(xb + rg + o0 + 256);
                split8(a, b, AH, AL);
                *(short8*)(fpl + tt * FST + 2048 + fo) = AH;
                *(short8*)(fpl + tt * FST + 3072 + fo) = AL;
            } else {                    // w1/w3: xR of tile tt
                const char* xb = xbase + tt * TS + 2048;
                const f32x4 a = *(const f32x4*)(xb + rg + o0);
                const f32x4 b = *(const f32x4*)(xb + rg + o0 + 256);
                short8 AH, AL;
                split8(a, b, AH, AL);
                *(short8*)(fpl + tt * FST + 4096 + fo) = AH;
                *(short8*)(fpl + tt * FST + 5120 + fo) = AL;
            }
        } else if (w <= 1) {
            short8 AH, AL;
            split8(c0, c1, AH, AL);
            *(short8*)(fpl + w * FST + fo)        = AH;
            *(short8*)(fpl + w * FST + 1024 + fo) = AL;
        }

        // ---- stores: tiles 2p, 2p+1 ----
#pragma unroll
        for (int tt = 0; tt < 2; ++tt) {
            const int T = 2 * p + tt;
            if (FINAL) {
                float* out = (float*)eout_;
                f32x4 v;
#pragma unroll
                for (int i = 0; i < 4; ++i) v[i] = fmaxf(acc[tt][0][i] + acc[tt][1][i], 0.f);
                *(f32x4*)(out + (size_t)(T * 16 + cidx) * 64 + 16 * w + 4 * g) = v;
            } else {
                char* out = (char*)eout_;
                const size_t rb = (size_t)(T * 16 + cidx) * 256;
                unsigned h0, l0, h1, l1;
                split2(fmaxf(acc[tt][0][0] + acc[tt][1][0], 0.f), fmaxf(acc[tt][0][1] + acc[tt][1][1], 0.f), h0, l0);
                split2(fmaxf(acc[tt][0][2] + acc[tt][1][2], 0.f), fmaxf(acc[tt][0][3] + acc[tt][1][3], 0.f), h1, l1);
                *(uint2*)(out + rb + colb)       = uint2{h0, h1};
                *(uint2*)(out + rb + 128 + colb) = uint2{l0, l1};
            }
        }
        barrier_nv();   // B
        sA = nA; sB = nB;
    }
}

extern "C" void kernel_launch(void* const* d_in, const int* in_sizes, int n_in,
                              void* d_out, int out_size, void* d_ws, size_t ws_size,
                              hipStream_t stream) {
    // inputs: contents0..8 = d_in[0..8], children0..7 = d_in[9..16],
    //         Wu = d_in[17], bu = d_in[18], Wh = d_in[19], bh = d_in[20]
    const float* Wu = (const float*)d_in[17];
    const float* bu = (const float*)d_in[18];
    const float* Wh = (const float*)d_in[19];
    const float* bh = (const float*)d_in[20];

    // emb_j stored as bf16 hi/lo planes, 256B/row
    void* bufA = d_ws;                               // emb7/5/3/1
    void* bufB = (char*)d_ws + (size_t)268435456;    // emb6/4/2

    const void* ein = d_in[8];  // contents8 (fp32) for the fused leaf level
    for (int j = 7; j >= 0; --j) {
        const int n      = in_sizes[j] / 32;
        const int npairs = n / 32;
        void* eout = (j == 0) ? d_out : ((j & 1) ? bufA : bufB);
        int blocks = npairs < 4096 ? npairs : 4096;
        const float* cont  = (const float*)d_in[j];
        const int*   child = (const int*)d_in[9 + j];
        if (j == 7)
            grnn_mfma<true,  false><<<blocks, 256, 0, stream>>>(cont, child, ein, Wu, bu, Wh, bh, eout, npairs);
        else if (j == 0)
            grnn_mfma<false, true ><<<blocks, 256, 0, stream>>>(cont, child, ein, Wu, bu, Wh, bh, eout, npairs);
        else
            grnn_mfma<false, false><<<blocks, 256, 0, stream>>>(cont, child, ein, Wu, bu, Wh, bh, eout, npairs);
        ein = eout;
    }
}

// Round 14
// 390.668 us; speedup vs baseline: 2.3606x; 1.3071x over previous
//
#include <hip/hip_runtime.h>
#include <hip/hip_bf16.h>

typedef __attribute__((ext_vector_type(8))) short  short8;
typedef __attribute__((ext_vector_type(4))) float  f32x4;

#define MFMA16(A,B,C) __builtin_amdgcn_mfma_f32_16x16x32_bf16((A),(B),(C),0,0,0)

// LDS-visibility barrier WITHOUT the vmcnt drain (T3/T4).
__device__ __forceinline__ void barrier_nv() {
    __builtin_amdgcn_sched_barrier(0);
    asm volatile("s_waitcnt lgkmcnt(0)" ::: "memory");
    __builtin_amdgcn_s_barrier();
    __builtin_amdgcn_sched_barrier(0);
}
// counted vmem wait (vmcnt retires in issue order: waits the oldest ops)
#define VM_WAIT(N) do { asm volatile("s_waitcnt vmcnt(" #N ")" ::: "memory"); \
                        __builtin_amdgcn_sched_barrier(0); } while (0)

// ---- fp32 -> bf16 hi/lo split, pair-packed (cvt_pk path) ----
__device__ __forceinline__ void split2(float x0, float x1, unsigned &hp, unsigned &lp) {
    __hip_bfloat162 h = __float22bfloat162_rn(float2{x0, x1});
    union { __hip_bfloat162 b; unsigned u; } uh, ul;
    uh.b = h;
    float f0 = __bfloat162float(h.x);
    float f1 = __bfloat162float(h.y);
    ul.b = __float22bfloat162_rn(float2{x0 - f0, x1 - f1});
    hp = uh.u; lp = ul.u;
}
// hi-only pack (for emb storage: single-bf16 rows)
__device__ __forceinline__ unsigned pack2(float x0, float x1) {
    union { __hip_bfloat162 b; unsigned u; } v;
    v.b = __float22bfloat162_rn(float2{x0, x1});
    return v.u;
}

__device__ __forceinline__ void split8(const f32x4 a, const f32x4 b, short8 &h, short8 &l) {
    union { short8 s; unsigned u[4]; } H, L;
    split2(a[0], a[1], H.u[0], L.u[0]);
    split2(a[2], a[3], H.u[1], L.u[1]);
    split2(b[0], b[1], H.u[2], L.u[2]);
    split2(b[2], b[3], H.u[3], L.u[3]);
    h = H.s; l = L.s;
}

// XOR-swizzled byte offset inside a [16 rows][64 bf16] plane (row stride 128B).
__device__ __forceinline__ unsigned swz(unsigned row, unsigned colbyte) {
    return row * 128u + (colbyte ^ ((row & 7u) << 4));
}

// async global->LDS, 16B/lane (per-lane global addr, lane-linear LDS dest).
__device__ __forceinline__ void gld16(const void* g, void* l) {
    __builtin_amdgcn_global_load_lds(
        (const __attribute__((address_space(1))) unsigned int*)g,
        (__attribute__((address_space(3))) unsigned int*)l, 16, 0, 0);
}

// Tree level, transposed-MFMA, pair-per-iteration (R13 skeleton).
// emb storage is now SINGLE bf16 (128B/row): gather bytes and store bytes
// halve; mid h-slots use 2 MFMAs (aH*WhH + aH*WhL; stored residual dropped,
// weight residual kept). u planes stay hi/lo (local). Staging layout is now
// identical for leaf (contents8 fp32 rows, 128B) and mid (emb bf16 rows, 128B):
// wave w stages (tile=w>>1, side=w&1) via 2x gld16.
template<bool LEAF, bool FINAL>
__global__ __launch_bounds__(256, 3)
void grnn_mfma(const float* __restrict__ cont,   // rows x 32 (fp32)
               const int*   __restrict__ child,  // rows x 2
               const void*  __restrict__ ein_,   // emb bf16 rows / contents8 fp32 rows (128B)
               const float* __restrict__ Wu,     // 32 x 64
               const float* __restrict__ bu,     // 64
               const float* __restrict__ Wh,     // 192 x 64
               const float* __restrict__ bh,     // 64
               void*        __restrict__ eout_,  // bf16 rows (fp32 if FINAL)
               int npairs)                        // ntiles/2
{
    constexpr int TS  = 4096;                 // staging bytes per tile (2 sides x 2KB)
    constexpr int STG = 2 * TS;               // per parity (one pair)
    constexpr int NPL = LEAF ? 6 : 2;
    constexpr int NFP = LEAF ? 3 : 1;
    constexpr int UST = NPL * 2048;
    constexpr int FST = NFP * 2048;
    __shared__ __align__(16) char lds[2 * STG + 2 * UST + 2 * FST];
    char* ub  = lds + 2 * STG;
    char* fpl = ub + 2 * UST;

    const int lane = threadIdx.x & 63;
    const int w    = threadIdx.x >> 6;
    const int cidx = lane & 15;
    const int g    = lane >> 4;

    // ---- weight fragments (hi/lo), transposed orientation ----
    short8 WhH[6], WhL[6], WuH, WuL;
#pragma unroll
    for (int s = 0; s < 6; ++s) {
        union { short8 s8; unsigned u[4]; } H, L;
#pragma unroll
        for (int q = 0; q < 4; ++q) {
            const int k = 32 * s + 8 * g + 2 * q;
            split2(Wh[k * 64 + 16 * w + cidx], Wh[(k + 1) * 64 + 16 * w + cidx], H.u[q], L.u[q]);
        }
        WhH[s] = H.s8; WhL[s] = L.s8;
    }
    {
        union { short8 s8; unsigned u[4]; } H, L;
#pragma unroll
        for (int q = 0; q < 4; ++q) {
            const int k = 8 * g + 2 * q;
            split2(Wu[k * 64 + 16 * w + cidx], Wu[(k + 1) * 64 + 16 * w + cidx], H.u[q], L.u[q]);
        }
        WuH = H.s8; WuL = L.s8;
    }
    const f32x4 bu4 = *(const f32x4*)(bu + 16 * w + 4 * g);
    const f32x4 bh4 = *(const f32x4*)(bh + 16 * w + 4 * g);

    const char* eb = (const char*)ein_;
    const unsigned colb = 32u * w + 8u * g;
    const int S = gridDim.x;

    const int stile = w >> 1, sside = w & 1;   // staging share: (tile, side)
    const unsigned fo = (unsigned)g * 256u + (unsigned)cidx * 16u;
    const unsigned o0 = 512u * (g & 1) + 16u * cidx;
    const unsigned rg = (unsigned)(g >> 1) * 1024u;

    int p = blockIdx.x;
    const int p1 = (p + S < npairs) ? p + S : p;
    const int ps0 = LEAF ? ((p + 2 * S < npairs) ? p + 2 * S : p) : p1;

    int2 sA, sB;   // child rows of the pair staged at the next staging point

    // ---- prologue ----
    {
        const int2 cA = *(const int2*)(child + 2 * (2 * p * 16 + cidx));
        const int2 cB = *(const int2*)(child + 2 * ((2 * p + 1) * 16 + cidx));
        { int2 ch = stile ? cB : cA; const int c = sside ? ch.y : ch.x;
          char* d = lds + 0 * STG + stile * TS + sside * 2048;
          gld16(eb + (size_t)c * 128 +      g * 16, d);
          gld16(eb + (size_t)c * 128 + 64 + g * 16, d + 1024); }
        if (LEAF) {
            const int2 dA = *(const int2*)(child + 2 * (2 * p1 * 16 + cidx));
            const int2 dB = *(const int2*)(child + 2 * ((2 * p1 + 1) * 16 + cidx));
            int2 ch = stile ? dB : dA; const int c = sside ? ch.y : ch.x;
            char* d = lds + 1 * STG + stile * TS + sside * 2048;
            gld16(eb + (size_t)c * 128 +      g * 16, d);
            gld16(eb + (size_t)c * 128 + 64 + g * 16, d + 1024);
        }
        sA = *(const int2*)(child + 2 * (2 * ps0 * 16 + cidx));
        sB = *(const int2*)(child + 2 * ((2 * ps0 + 1) * 16 + cidx));
    }
    f32x4 c0, c1;
    if (w == 0) {
        const f32x4* pc = (const f32x4*)(cont + (size_t)(2 * p * 16 + cidx) * 32 + 8 * g);
        c0 = pc[0]; c1 = pc[1];
    } else if (w == (LEAF ? 2 : 1)) {
        const f32x4* pc = (const f32x4*)(cont + (size_t)((2 * p + 1) * 16 + cidx) * 32 + 8 * g);
        c0 = pc[0]; c1 = pc[1];
    }
    __syncthreads();   // full drain: prologue staging + regs complete

    // prologue frag jobs for pair p
    if (LEAF) {
        const int tt = w >> 1;
        if ((w & 1) == 0) {
            short8 AH, AL;
            split8(c0, c1, AH, AL);
            *(short8*)(fpl + tt * FST + fo)        = AH;
            *(short8*)(fpl + tt * FST + 1024 + fo) = AL;
            const char* xb = lds + 0 * STG + tt * TS;
            const f32x4 a = *(const f32x4*)(xb + rg + o0);
            const f32x4 b = *(const f32x4*)(xb + rg + o0 + 256);
            split8(a, b, AH, AL);
            *(short8*)(fpl + tt * FST + 2048 + fo) = AH;
            *(short8*)(fpl + tt * FST + 3072 + fo) = AL;
        } else {
            const char* xb = lds + 0 * STG + tt * TS + 2048;
            const f32x4 a = *(const f32x4*)(xb + rg + o0);
            const f32x4 b = *(const f32x4*)(xb + rg + o0 + 256);
            short8 AH, AL;
            split8(a, b, AH, AL);
            *(short8*)(fpl + tt * FST + 4096 + fo) = AH;
            *(short8*)(fpl + tt * FST + 5120 + fo) = AL;
        }
    } else if (w <= 1) {
        short8 AH, AL;
        split8(c0, c1, AH, AL);
        *(short8*)(fpl + w * FST + fo)        = AH;
        *(short8*)(fpl + w * FST + 1024 + fo) = AL;
    }
    __syncthreads();

    for (int k = 0; p < npairs; p += S, ++k) {
        const int pb = k & 1;
        const int pf = (p + S < npairs) ? p + S : p;
        const int pn = LEAF ? ((p + 3 * S < npairs) ? p + 3 * S : p)
                            : ((p + 2 * S < npairs) ? p + 2 * S : p);

        // ---- phase 1: u-GEMMs for both tiles of pair p ----
#pragma unroll
        for (int tt = 0; tt < 2; ++tt) {
            const short8 aH = *(const short8*)(fpl + tt * FST + fo);
            const short8 aL = *(const short8*)(fpl + tt * FST + 1024 + fo);
            f32x4 ua = bu4;
            ua = MFMA16(WuH, aH, ua);
            ua = MFMA16(WuL, aH, ua);
            ua = MFMA16(WuH, aL, ua);
            const unsigned off = swz(cidx, colb);
            unsigned h0, l0, h1, l1;
            split2(fmaxf(ua[0], 0.f), fmaxf(ua[1], 0.f), h0, l0);
            split2(fmaxf(ua[2], 0.f), fmaxf(ua[3], 0.f), h1, l1);
            *(uint2*)(ub + tt * UST + (NPL - 2) * 2048 + off) = uint2{h0, h1};
            *(uint2*)(ub + tt * UST + (NPL - 1) * 2048 + off) = uint2{l0, l1};
            if (LEAF) {
#pragma unroll
                for (int sd = 0; sd < 2; ++sd) {
                    const short8 xH = *(const short8*)(fpl + tt * FST + (1 + sd) * 2048 + fo);
                    const short8 xL = *(const short8*)(fpl + tt * FST + (1 + sd) * 2048 + 1024 + fo);
                    f32x4 ux = bu4;
                    ux = MFMA16(WuH, xH, ux);
                    ux = MFMA16(WuL, xH, ux);
                    ux = MFMA16(WuH, xL, ux);
                    split2(fmaxf(ux[0], 0.f), fmaxf(ux[1], 0.f), h0, l0);
                    split2(fmaxf(ux[2], 0.f), fmaxf(ux[3], 0.f), h1, l1);
                    *(uint2*)(ub + tt * UST + (2 * sd + 0) * 2048 + off) = uint2{h0, h1};
                    *(uint2*)(ub + tt * UST + (2 * sd + 1) * 2048 + off) = uint2{l0, l1};
                }
            }
        }
        if (!LEAF) VM_WAIT(0);   // own staging drained pre-A -> visible to ALL post-A
        barrier_nv();            // A

        // ---- phase 2 ----
        if (w == 0) {
            const f32x4* pc = (const f32x4*)(cont + (size_t)(2 * pf * 16 + cidx) * 32 + 8 * g);
            c0 = pc[0]; c1 = pc[1];
        } else if (w == (LEAF ? 2 : 1)) {
            const f32x4* pc = (const f32x4*)(cont + (size_t)((2 * pf + 1) * 16 + cidx) * 32 + 8 * g);
            c0 = pc[0]; c1 = pc[1];
        }
        // stage next pair from pipelined child regs (unified 128B-row form)
        {
            int2 ch = stile ? sB : sA; const int c = sside ? ch.y : ch.x;
            char* d = lds + (LEAF ? pb : (pb ^ 1)) * STG + stile * TS + sside * 2048;
            gld16(eb + (size_t)c * 128 +      g * 16, d);
            gld16(eb + (size_t)c * 128 + 64 + g * 16, d + 1024);
        }
        __builtin_amdgcn_sched_barrier(0);
        int2 nA = *(const int2*)(child + 2 * (2 * pn * 16 + cidx));
        int2 nB = *(const int2*)(child + 2 * ((2 * pn + 1) * 16 + cidx));

        // h-GEMMs (4 independent accumulator chains)
        f32x4 acc[2][2];
        acc[0][0] = bh4; acc[0][1] = f32x4{0.f, 0.f, 0.f, 0.f};
        acc[1][0] = bh4; acc[1][1] = f32x4{0.f, 0.f, 0.f, 0.f};
        if (LEAF) {
#pragma unroll
            for (int tt = 0; tt < 2; ++tt)
#pragma unroll
            for (int q = 0; q < 3; ++q)
#pragma unroll
            for (int s = 0; s < 2; ++s) {
                const short8 aH = *(const short8*)(ub + tt * UST + (2 * q + 0) * 2048 + swz(cidx, 64 * s + 16 * g));
                const short8 aL = *(const short8*)(ub + tt * UST + (2 * q + 1) * 2048 + swz(cidx, 64 * s + 16 * g));
                const int Sl = 2 * q + s;
                acc[tt][s] = MFMA16(WhH[Sl], aH, acc[tt][s]);
                acc[tt][s] = MFMA16(WhL[Sl], aH, acc[tt][s]);
                acc[tt][s] = MFMA16(WhH[Sl], aL, acc[tt][s]);
            }
        } else {
#pragma unroll
            for (int tt = 0; tt < 2; ++tt) {
                const char* hb = lds + pb * STG + tt * TS;
#pragma unroll
                for (int sd = 0; sd < 2; ++sd)
#pragma unroll
                for (int s = 0; s < 2; ++s) {
                    const short8 aH = *(const short8*)(hb + sd * 2048 + s * 1024 + 16 * lane);
                    const int Sl = 2 * sd + s;
                    acc[tt][sd] = MFMA16(WhH[Sl], aH, acc[tt][sd]);
                    acc[tt][sd] = MFMA16(WhL[Sl], aH, acc[tt][sd]);
                }
#pragma unroll
                for (int s = 0; s < 2; ++s) {
                    const short8 aH = *(const short8*)(ub + tt * UST + 0 * 2048 + swz(cidx, 64 * s + 16 * g));
                    const short8 aL = *(const short8*)(ub + tt * UST + 1 * 2048 + swz(cidx, 64 * s + 16 * g));
                    const int Sl = 4 + s;
                    acc[tt][s] = MFMA16(WhH[Sl], aH, acc[tt][s]);
                    acc[tt][s] = MFMA16(WhL[Sl], aH, acc[tt][s]);
                    acc[tt][s] = MFMA16(WhH[Sl], aL, acc[tt][s]);
                }
            }
        }

        // split-jobs for pair pf
        if (LEAF) {
            VM_WAIT(4);   // keep this iter's 2 staging + 2 child; older drained
            const char* xbase = lds + (pb ^ 1) * STG;
            const int tt = w >> 1;
            if ((w & 1) == 0) {
                short8 AH, AL;
                split8(c0, c1, AH, AL);
                *(short8*)(fpl + tt * FST + fo)        = AH;
                *(short8*)(fpl + tt * FST + 1024 + fo) = AL;
                const char* xb = xbase + tt * TS;
                const f32x4 a = *(const f32x4*)(xb + rg + o0);
                const f32x4 b = *(const f32x4*)(xb + rg + o0 + 256);
                split8(a, b, AH, AL);
                *(short8*)(fpl + tt * FST + 2048 + fo) = AH;
                *(short8*)(fpl + tt * FST + 3072 + fo) = AL;
            } else {
                const char* xb = xbase + tt * TS + 2048;
                const f32x4 a = *(const f32x4*)(xb + rg + o0);
                const f32x4 b = *(const f32x4*)(xb + rg + o0 + 256);
                short8 AH, AL;
                split8(a, b, AH, AL);
                *(short8*)(fpl + tt * FST + 4096 + fo) = AH;
                *(short8*)(fpl + tt * FST + 5120 + fo) = AL;
            }
        } else if (w <= 1) {
            short8 AH, AL;
            split8(c0, c1, AH, AL);
            *(short8*)(fpl + w * FST + fo)        = AH;
            *(short8*)(fpl + w * FST + 1024 + fo) = AL;
        }

        // ---- stores: tiles 2p, 2p+1 (bf16 128B rows; fp32 if FINAL) ----
#pragma unroll
        for (int tt = 0; tt < 2; ++tt) {
            const int T = 2 * p + tt;
            if (FINAL) {
                float* out = (float*)eout_;
                f32x4 v;
#pragma unroll
                for (int i = 0; i < 4; ++i) v[i] = fmaxf(acc[tt][0][i] + acc[tt][1][i], 0.f);
                *(f32x4*)(out + (size_t)(T * 16 + cidx) * 64 + 16 * w + 4 * g) = v;
            } else {
                char* out = (char*)eout_;
                const size_t rb = (size_t)(T * 16 + cidx) * 128;
                unsigned h0 = pack2(fmaxf(acc[tt][0][0] + acc[tt][1][0], 0.f),
                                    fmaxf(acc[tt][0][1] + acc[tt][1][1], 0.f));
                unsigned h1 = pack2(fmaxf(acc[tt][0][2] + acc[tt][1][2], 0.f),
                                    fmaxf(acc[tt][0][3] + acc[tt][1][3], 0.f));
                *(uint2*)(out + rb + colb) = uint2{h0, h1};
            }
        }
        barrier_nv();   // B
        sA = nA; sB = nB;
    }
}

extern "C" void kernel_launch(void* const* d_in, const int* in_sizes, int n_in,
                              void* d_out, int out_size, void* d_ws, size_t ws_size,
                              hipStream_t stream) {
    // inputs: contents0..8 = d_in[0..8], children0..7 = d_in[9..16],
    //         Wu = d_in[17], bu = d_in[18], Wh = d_in[19], bh = d_in[20]
    const float* Wu = (const float*)d_in[17];
    const float* bu = (const float*)d_in[18];
    const float* Wh = (const float*)d_in[19];
    const float* bh = (const float*)d_in[20];

    // emb_j stored as single-bf16 rows, 128B/row
    void* bufA = d_ws;                               // emb7/5/3/1
    void* bufB = (char*)d_ws + (size_t)268435456;    // emb6/4/2

    const void* ein = d_in[8];  // contents8 (fp32) for the fused leaf level
    for (int j = 7; j >= 0; --j) {
        const int n      = in_sizes[j] / 32;
        const int npairs = n / 32;
        void* eout = (j == 0) ? d_out : ((j & 1) ? bufA : bufB);
        int blocks = npairs < 4096 ? npairs : 4096;
        const float* cont  = (const float*)d_in[j];
        const int*   child = (const int*)d_in[9 + j];
        if (j == 7)
            grnn_mfma<true,  false><<<blocks, 256, 0, stream>>>(cont, child, ein, Wu, bu, Wh, bh, eout, npairs);
        else if (j == 0)
            grnn_mfma<false, true ><<<blocks, 256, 0, stream>>>(cont, child, ein, Wu, bu, Wh, bh, eout, npairs);
        else
            grnn_mfma<false, false><<<blocks, 256, 0, stream>>>(cont, child, ein, Wu, bu, Wh, bh, eout, npairs);
        ein = eout;
    }
}

// Round 16
// 354.224 us; speedup vs baseline: 2.6034x; 1.1029x over previous
//
#include <hip/hip_runtime.h>
#include <hip/hip_bf16.h>

typedef __attribute__((ext_vector_type(8))) short  short8;
typedef __attribute__((ext_vector_type(4))) float  f32x4;

#define MFMA16(A,B,C) __builtin_amdgcn_mfma_f32_16x16x32_bf16((A),(B),(C),0,0,0)

// LDS-visibility barrier WITHOUT the vmcnt drain (used only at B, where no
// vmem-produced data is consumed before the next A's vmcnt(0)).
__device__ __forceinline__ void barrier_nv() {
    __builtin_amdgcn_sched_barrier(0);
    asm volatile("s_waitcnt lgkmcnt(0)" ::: "memory");
    __builtin_amdgcn_s_barrier();
    __builtin_amdgcn_sched_barrier(0);
}
#define VM_WAIT0() do { asm volatile("s_waitcnt vmcnt(0)" ::: "memory"); \
                        __builtin_amdgcn_sched_barrier(0); } while (0)

// ---- fp32 -> bf16 hi/lo split, pair-packed (cvt_pk path) ----
__device__ __forceinline__ void split2(float x0, float x1, unsigned &hp, unsigned &lp) {
    __hip_bfloat162 h = __float22bfloat162_rn(float2{x0, x1});
    union { __hip_bfloat162 b; unsigned u; } uh, ul;
    uh.b = h;
    float f0 = __bfloat162float(h.x);
    float f1 = __bfloat162float(h.y);
    ul.b = __float22bfloat162_rn(float2{x0 - f0, x1 - f1});
    hp = uh.u; lp = ul.u;
}
// hi-only pack (emb storage rows + u planes)
__device__ __forceinline__ unsigned pack2(float x0, float x1) {
    union { __hip_bfloat162 b; unsigned u; } v;
    v.b = __float22bfloat162_rn(float2{x0, x1});
    return v.u;
}

__device__ __forceinline__ void split8(const f32x4 a, const f32x4 b, short8 &h, short8 &l) {
    union { short8 s; unsigned u[4]; } H, L;
    split2(a[0], a[1], H.u[0], L.u[0]);
    split2(a[2], a[3], H.u[1], L.u[1]);
    split2(b[0], b[1], H.u[2], L.u[2]);
    split2(b[2], b[3], H.u[3], L.u[3]);
    h = H.s; l = L.s;
}

// XOR-swizzled byte offset inside a [16 rows][64 bf16] plane (row stride 128B).
__device__ __forceinline__ unsigned swz(unsigned row, unsigned colbyte) {
    return row * 128u + (colbyte ^ ((row & 7u) << 4));
}

// async global->LDS, 16B/lane (per-lane global addr, lane-linear LDS dest).
__device__ __forceinline__ void gld16(const void* g, void* l) {
    __builtin_amdgcn_global_load_lds(
        (const __attribute__((address_space(1))) unsigned int*)g,
        (__attribute__((address_space(3))) unsigned int*)l, 16, 0, 0);
}

// Tree level, transposed-MFMA, pair-per-iteration (R15 numerics, R16 sync):
// EVERY iteration drains vmcnt(0) before barrier A -> all gld16 staging
// (issued at phase2 of the previous iteration) is provably complete and
// visible to all waves before any consumption. No count-based vm waits.
template<bool LEAF, bool FINAL>
__global__ __launch_bounds__(256, 3)
void grnn_mfma(const float* __restrict__ cont,   // rows x 32 (fp32)
               const int*   __restrict__ child,  // rows x 2
               const void*  __restrict__ ein_,   // emb bf16 rows / contents8 fp32 rows (128B)
               const float* __restrict__ Wu,     // 32 x 64
               const float* __restrict__ bu,     // 64
               const float* __restrict__ Wh,     // 192 x 64
               const float* __restrict__ bh,     // 64
               void*        __restrict__ eout_,  // bf16 rows (fp32 if FINAL)
               int npairs)                        // ntiles/2
{
    constexpr int TS  = 4096;                 // staging bytes per tile (2 sides x 2KB)
    constexpr int STG = 2 * TS;               // per parity (one pair)
    constexpr int NPL = LEAF ? 3 : 1;         // u planes (hi only): [uL,uR,]u
    constexpr int NFP = LEAF ? 3 : 1;         // frag planes (hi+lo pairs)
    constexpr int UST = NPL * 2048;
    constexpr int FST = NFP * 2048;
    __shared__ __align__(16) char lds[2 * STG + 2 * UST + 2 * FST];
    char* ub  = lds + 2 * STG;
    char* fpl = ub + 2 * UST;

    const int lane = threadIdx.x & 63;
    const int w    = threadIdx.x >> 6;
    const int cidx = lane & 15;
    const int g    = lane >> 4;

    // ---- weight fragments (hi/lo), transposed orientation ----
    short8 WhH[6], WhL[6], WuH, WuL;
#pragma unroll
    for (int s = 0; s < 6; ++s) {
        union { short8 s8; unsigned u[4]; } H, L;
#pragma unroll
        for (int q = 0; q < 4; ++q) {
            const int k = 32 * s + 8 * g + 2 * q;
            split2(Wh[k * 64 + 16 * w + cidx], Wh[(k + 1) * 64 + 16 * w + cidx], H.u[q], L.u[q]);
        }
        WhH[s] = H.s8; WhL[s] = L.s8;
    }
    {
        union { short8 s8; unsigned u[4]; } H, L;
#pragma unroll
        for (int q = 0; q < 4; ++q) {
            const int k = 8 * g + 2 * q;
            split2(Wu[k * 64 + 16 * w + cidx], Wu[(k + 1) * 64 + 16 * w + cidx], H.u[q], L.u[q]);
        }
        WuH = H.s8; WuL = L.s8;
    }
    const f32x4 bu4 = *(const f32x4*)(bu + 16 * w + 4 * g);
    const f32x4 bh4 = *(const f32x4*)(bh + 16 * w + 4 * g);

    const char* eb = (const char*)ein_;
    const unsigned colb = 32u * w + 8u * g;
    const int S = gridDim.x;

    const int stile = w >> 1, sside = w & 1;   // staging share: (tile, side)
    const unsigned fo = (unsigned)g * 256u + (unsigned)cidx * 16u;
    const unsigned o0 = 512u * (g & 1) + 16u * cidx;
    const unsigned rg = (unsigned)(g >> 1) * 1024u;

    int p = blockIdx.x;
    const int p1 = (p + S < npairs) ? p + S : p;
    const int ps0 = LEAF ? ((p + 2 * S < npairs) ? p + 2 * S : p) : p1;

    int2 sA, sB;   // child rows of the pair staged at the next staging point

    // ---- prologue ----
    {
        const int2 cA = *(const int2*)(child + 2 * (2 * p * 16 + cidx));
        const int2 cB = *(const int2*)(child + 2 * ((2 * p + 1) * 16 + cidx));
        { int2 ch = stile ? cB : cA; const int c = sside ? ch.y : ch.x;
          char* d = lds + 0 * STG + stile * TS + sside * 2048;
          gld16(eb + (size_t)c * 128 +      g * 16, d);
          gld16(eb + (size_t)c * 128 + 64 + g * 16, d + 1024); }
        if (LEAF) {
            const int2 dA = *(const int2*)(child + 2 * (2 * p1 * 16 + cidx));
            const int2 dB = *(const int2*)(child + 2 * ((2 * p1 + 1) * 16 + cidx));
            int2 ch = stile ? dB : dA; const int c = sside ? ch.y : ch.x;
            char* d = lds + 1 * STG + stile * TS + sside * 2048;
            gld16(eb + (size_t)c * 128 +      g * 16, d);
            gld16(eb + (size_t)c * 128 + 64 + g * 16, d + 1024);
        }
        sA = *(const int2*)(child + 2 * (2 * ps0 * 16 + cidx));
        sB = *(const int2*)(child + 2 * ((2 * ps0 + 1) * 16 + cidx));
    }
    f32x4 c0, c1;
    if (w == 0) {
        const f32x4* pc = (const f32x4*)(cont + (size_t)(2 * p * 16 + cidx) * 32 + 8 * g);
        c0 = pc[0]; c1 = pc[1];
    } else if (w == (LEAF ? 2 : 1)) {
        const f32x4* pc = (const f32x4*)(cont + (size_t)((2 * p + 1) * 16 + cidx) * 32 + 8 * g);
        c0 = pc[0]; c1 = pc[1];
    }
    __syncthreads();   // full drain: prologue staging + regs complete

    // prologue frag jobs for pair p
    if (LEAF) {
        const int tt = w >> 1;
        if ((w & 1) == 0) {
            short8 AH, AL;
            split8(c0, c1, AH, AL);
            *(short8*)(fpl + tt * FST + fo)        = AH;
            *(short8*)(fpl + tt * FST + 1024 + fo) = AL;
            const char* xb = lds + 0 * STG + tt * TS;
            const f32x4 a = *(const f32x4*)(xb + rg + o0);
            const f32x4 b = *(const f32x4*)(xb + rg + o0 + 256);
            split8(a, b, AH, AL);
            *(short8*)(fpl + tt * FST + 2048 + fo) = AH;
            *(short8*)(fpl + tt * FST + 3072 + fo) = AL;
        } else {
            const char* xb = lds + 0 * STG + tt * TS + 2048;
            const f32x4 a = *(const f32x4*)(xb + rg + o0);
            const f32x4 b = *(const f32x4*)(xb + rg + o0 + 256);
            short8 AH, AL;
            split8(a, b, AH, AL);
            *(short8*)(fpl + tt * FST + 4096 + fo) = AH;
            *(short8*)(fpl + tt * FST + 5120 + fo) = AL;
        }
    } else if (w <= 1) {
        short8 AH, AL;
        split8(c0, c1, AH, AL);
        *(short8*)(fpl + w * FST + fo)        = AH;
        *(short8*)(fpl + w * FST + 1024 + fo) = AL;
    }
    __syncthreads();

    for (int k = 0; p < npairs; p += S, ++k) {
        const int pb = k & 1;
        const int pf = (p + S < npairs) ? p + S : p;
        const int pn = LEAF ? ((p + 3 * S < npairs) ? p + 3 * S : p)
                            : ((p + 2 * S < npairs) ? p + 2 * S : p);

        // ---- phase 1: u-GEMMs for both tiles of pair p; hi-only stash ----
#pragma unroll
        for (int tt = 0; tt < 2; ++tt) {
            const short8 aH = *(const short8*)(fpl + tt * FST + fo);
            const short8 aL = *(const short8*)(fpl + tt * FST + 1024 + fo);
            f32x4 ua = bu4;
            ua = MFMA16(WuH, aH, ua);
            ua = MFMA16(WuL, aH, ua);
            ua = MFMA16(WuH, aL, ua);
            const unsigned off = swz(cidx, colb);
            {
                unsigned h0 = pack2(fmaxf(ua[0], 0.f), fmaxf(ua[1], 0.f));
                unsigned h1 = pack2(fmaxf(ua[2], 0.f), fmaxf(ua[3], 0.f));
                *(uint2*)(ub + tt * UST + (NPL - 1) * 2048 + off) = uint2{h0, h1};
            }
            if (LEAF) {
#pragma unroll
                for (int sd = 0; sd < 2; ++sd) {
                    const short8 xH = *(const short8*)(fpl + tt * FST + (1 + sd) * 2048 + fo);
                    const short8 xL = *(const short8*)(fpl + tt * FST + (1 + sd) * 2048 + 1024 + fo);
                    f32x4 ux = bu4;
                    ux = MFMA16(WuH, xH, ux);
                    ux = MFMA16(WuL, xH, ux);
                    ux = MFMA16(WuH, xL, ux);
                    unsigned h0 = pack2(fmaxf(ux[0], 0.f), fmaxf(ux[1], 0.f));
                    unsigned h1 = pack2(fmaxf(ux[2], 0.f), fmaxf(ux[3], 0.f));
                    *(uint2*)(ub + tt * UST + sd * 2048 + off) = uint2{h0, h1};
                }
            }
        }
        VM_WAIT0();      // ALL prior staging complete (canonical gld16 pattern)
        barrier_nv();    // A: staged buffers + u planes visible to all waves

        // ---- phase 2 ----
        if (w == 0) {
            const f32x4* pc = (const f32x4*)(cont + (size_t)(2 * pf * 16 + cidx) * 32 + 8 * g);
            c0 = pc[0]; c1 = pc[1];
        } else if (w == (LEAF ? 2 : 1)) {
            const f32x4* pc = (const f32x4*)(cont + (size_t)((2 * pf + 1) * 16 + cidx) * 32 + 8 * g);
            c0 = pc[0]; c1 = pc[1];
        }
        // stage next pair from pipelined child regs (128B-row form); drained
        // at the NEXT iteration's VM_WAIT0-before-A, consumed after that A.
        {
            int2 ch = stile ? sB : sA; const int c = sside ? ch.y : ch.x;
            char* d = lds + (LEAF ? pb : (pb ^ 1)) * STG + stile * TS + sside * 2048;
            gld16(eb + (size_t)c * 128 +      g * 16, d);
            gld16(eb + (size_t)c * 128 + 64 + g * 16, d + 1024);
        }
        __builtin_amdgcn_sched_barrier(0);
        int2 nA = *(const int2*)(child + 2 * (2 * pn * 16 + cidx));
        int2 nB = *(const int2*)(child + 2 * ((2 * pn + 1) * 16 + cidx));

        // h-GEMMs: every slot = 2 MFMAs (hi activation x hi/lo weight)
        f32x4 acc[2][2];
        acc[0][0] = bh4; acc[0][1] = f32x4{0.f, 0.f, 0.f, 0.f};
        acc[1][0] = bh4; acc[1][1] = f32x4{0.f, 0.f, 0.f, 0.f};
        if (LEAF) {
#pragma unroll
            for (int tt = 0; tt < 2; ++tt)
#pragma unroll
            for (int q = 0; q < 3; ++q)
#pragma unroll
            for (int s = 0; s < 2; ++s) {
                const short8 aH = *(const short8*)(ub + tt * UST + q * 2048 + swz(cidx, 64 * s + 16 * g));
                const int Sl = 2 * q + s;
                acc[tt][s] = MFMA16(WhH[Sl], aH, acc[tt][s]);
                acc[tt][s] = MFMA16(WhL[Sl], aH, acc[tt][s]);
            }
        } else {
#pragma unroll
            for (int tt = 0; tt < 2; ++tt) {
                const char* hb = lds + pb * STG + tt * TS;
#pragma unroll
                for (int sd = 0; sd < 2; ++sd)
#pragma unroll
                for (int s = 0; s < 2; ++s) {
                    const short8 aH = *(const short8*)(hb + sd * 2048 + s * 1024 + 16 * lane);
                    const int Sl = 2 * sd + s;
                    acc[tt][sd] = MFMA16(WhH[Sl], aH, acc[tt][sd]);
                    acc[tt][sd] = MFMA16(WhL[Sl], aH, acc[tt][sd]);
                }
#pragma unroll
                for (int s = 0; s < 2; ++s) {
                    const short8 aH = *(const short8*)(ub + tt * UST + swz(cidx, 64 * s + 16 * g));
                    const int Sl = 4 + s;
                    acc[tt][s] = MFMA16(WhH[Sl], aH, acc[tt][s]);
                    acc[tt][s] = MFMA16(WhL[Sl], aH, acc[tt][s]);
                }
            }
        }

        // split-jobs for pair pf (leaf x-rows staged pre-previous-A -> visible)
        if (LEAF) {
            const char* xbase = lds + (pb ^ 1) * STG;
            const int tt = w >> 1;
            if ((w & 1) == 0) {
                short8 AH, AL;
                split8(c0, c1, AH, AL);
                *(short8*)(fpl + tt * FST + fo)        = AH;
                *(short8*)(fpl + tt * FST + 1024 + fo) = AL;
                const char* xb = xbase + tt * TS;
                const f32x4 a = *(const f32x4*)(xb + rg + o0);
                const f32x4 b = *(const f32x4*)(xb + rg + o0 + 256);
                split8(a, b, AH, AL);
                *(short8*)(fpl + tt * FST + 2048 + fo) = AH;
                *(short8*)(fpl + tt * FST + 3072 + fo) = AL;
            } else {
                const char* xb = xbase + tt * TS + 2048;
                const f32x4 a = *(const f32x4*)(xb + rg + o0);
                const f32x4 b = *(const f32x4*)(xb + rg + o0 + 256);
                short8 AH, AL;
                split8(a, b, AH, AL);
                *(short8*)(fpl + tt * FST + 4096 + fo) = AH;
                *(short8*)(fpl + tt * FST + 5120 + fo) = AL;
            }
        } else if (w <= 1) {
            short8 AH, AL;
            split8(c0, c1, AH, AL);
            *(short8*)(fpl + w * FST + fo)        = AH;
            *(short8*)(fpl + w * FST + 1024 + fo) = AL;
        }

        // ---- stores: tiles 2p, 2p+1 (bf16 128B rows; fp32 if FINAL) ----
#pragma unroll
        for (int tt = 0; tt < 2; ++tt) {
            const int T = 2 * p + tt;
            if (FINAL) {
                float* out = (float*)eout_;
                f32x4 v;
#pragma unroll
                for (int i = 0; i < 4; ++i) v[i] = fmaxf(acc[tt][0][i] + acc[tt][1][i], 0.f);
                *(f32x4*)(out + (size_t)(T * 16 + cidx) * 64 + 16 * w + 4 * g) = v;
            } else {
                char* out = (char*)eout_;
                const size_t rb = (size_t)(T * 16 + cidx) * 128;
                unsigned h0 = pack2(fmaxf(acc[tt][0][0] + acc[tt][1][0], 0.f),
                                    fmaxf(acc[tt][0][1] + acc[tt][1][1], 0.f));
                unsigned h1 = pack2(fmaxf(acc[tt][0][2] + acc[tt][1][2], 0.f),
                                    fmaxf(acc[tt][0][3] + acc[tt][1][3], 0.f));
                *(uint2*)(out + rb + colb) = uint2{h0, h1};
            }
        }
        barrier_nv();   // B: frag planes visible (ds ops only)
        sA = nA; sB = nB;
    }
}

extern "C" void kernel_launch(void* const* d_in, const int* in_sizes, int n_in,
                              void* d_out, int out_size, void* d_ws, size_t ws_size,
                              hipStream_t stream) {
    // inputs: contents0..8 = d_in[0..8], children0..7 = d_in[9..16],
    //         Wu = d_in[17], bu = d_in[18], Wh = d_in[19], bh = d_in[20]
    const float* Wu = (const float*)d_in[17];
    const float* bu = (const float*)d_in[18];
    const float* Wh = (const float*)d_in[19];
    const float* bh = (const float*)d_in[20];

    // emb_j stored as single-bf16 rows, 128B/row
    void* bufA = d_ws;                               // emb7/5/3/1
    void* bufB = (char*)d_ws + (size_t)268435456;    // emb6/4/2

    const void* ein = d_in[8];  // contents8 (fp32) for the fused leaf level
    for (int j = 7; j >= 0; --j) {
        const int n      = in_sizes[j] / 32;
        const int npairs = n / 32;
        void* eout = (j == 0) ? d_out : ((j & 1) ? bufA : bufB);
        int blocks = npairs < 4096 ? npairs : 4096;
        const float* cont  = (const float*)d_in[j];
        const int*   child = (const int*)d_in[9 + j];
        if (j == 7)
            grnn_mfma<true,  false><<<blocks, 256, 0, stream>>>(cont, child, ein, Wu, bu, Wh, bh, eout, npairs);
        else if (j == 0)
            grnn_mfma<false, true ><<<blocks, 256, 0, stream>>>(cont, child, ein, Wu, bu, Wh, bh, eout, npairs);
        else
            grnn_mfma<false, false><<<blocks, 256, 0, stream>>>(cont, child, ein, Wu, bu, Wh, bh, eout, npairs);
        ein = eout;
    }
}

// Round 17
// 348.272 us; speedup vs baseline: 2.6479x; 1.0171x over previous
//
#include <hip/hip_runtime.h>
#include <hip/hip_bf16.h>

typedef __attribute__((ext_vector_type(8))) short  short8;
typedef __attribute__((ext_vector_type(4))) float  f32x4;

#define MFMA16(A,B,C) __builtin_amdgcn_mfma_f32_16x16x32_bf16((A),(B),(C),0,0,0)

// LDS-visibility barrier WITHOUT the vmcnt drain (used only at B, where no
// vmem-produced data is consumed before the next A's vmcnt(0)).
__device__ __forceinline__ void barrier_nv() {
    __builtin_amdgcn_sched_barrier(0);
    asm volatile("s_waitcnt lgkmcnt(0)" ::: "memory");
    __builtin_amdgcn_s_barrier();
    __builtin_amdgcn_sched_barrier(0);
}
#define VM_WAIT0() do { asm volatile("s_waitcnt vmcnt(0)" ::: "memory"); \
                        __builtin_amdgcn_sched_barrier(0); } while (0)

// ---- fp32 -> bf16 hi/lo split (weights only keep the lo part) ----
__device__ __forceinline__ void split2(float x0, float x1, unsigned &hp, unsigned &lp) {
    __hip_bfloat162 h = __float22bfloat162_rn(float2{x0, x1});
    union { __hip_bfloat162 b; unsigned u; } uh, ul;
    uh.b = h;
    float f0 = __bfloat162float(h.x);
    float f1 = __bfloat162float(h.y);
    ul.b = __float22bfloat162_rn(float2{x0 - f0, x1 - f1});
    hp = uh.u; lp = ul.u;
}
// hi-only pack: 2 floats -> packed bf16x2 dword
__device__ __forceinline__ unsigned pack2(float x0, float x1) {
    union { __hip_bfloat162 b; unsigned u; } v;
    v.b = __float22bfloat162_rn(float2{x0, x1});
    return v.u;
}
// hi-only pack: 8 floats -> short8 fragment (4 cvt_pk)
__device__ __forceinline__ short8 pack8(const f32x4 a, const f32x4 b) {
    union { short8 s; unsigned u[4]; } H;
    H.u[0] = pack2(a[0], a[1]);
    H.u[1] = pack2(a[2], a[3]);
    H.u[2] = pack2(b[0], b[1]);
    H.u[3] = pack2(b[2], b[3]);
    return H.s;
}

// XOR-swizzled byte offset inside a [16 rows][64 bf16] plane (row stride 128B).
__device__ __forceinline__ unsigned swz(unsigned row, unsigned colbyte) {
    return row * 128u + (colbyte ^ ((row & 7u) << 4));
}

// async global->LDS, 16B/lane (per-lane global addr, lane-linear LDS dest).
__device__ __forceinline__ void gld16(const void* g, void* l) {
    __builtin_amdgcn_global_load_lds(
        (const __attribute__((address_space(1))) unsigned int*)g,
        (__attribute__((address_space(3))) unsigned int*)l, 16, 0, 0);
}

// Tree level, transposed-MFMA, pair-per-iteration (R16 sync, R17 numerics):
// ALL activations are hi-only bf16; only WEIGHTS carry hi+lo. Every GEMM slot
// (u and h) = 2 MFMAs: aH*W_H + aH*W_L. Frag planes are hi-only (1KB/plane).
// Sync: every iteration drains vmcnt(0) before barrier A (canonical gld16
// pattern, race-free by construction — no count-based waits).
template<bool LEAF, bool FINAL>
__global__ __launch_bounds__(256, 3)
void grnn_mfma(const float* __restrict__ cont,   // rows x 32 (fp32)
               const int*   __restrict__ child,  // rows x 2
               const void*  __restrict__ ein_,   // emb bf16 rows / contents8 fp32 rows (128B)
               const float* __restrict__ Wu,     // 32 x 64
               const float* __restrict__ bu,     // 64
               const float* __restrict__ Wh,     // 192 x 64
               const float* __restrict__ bh,     // 64
               void*        __restrict__ eout_,  // bf16 rows (fp32 if FINAL)
               int npairs)                        // ntiles/2
{
    constexpr int TS  = 4096;                 // staging bytes per tile (2 sides x 2KB)
    constexpr int STG = 2 * TS;               // per parity (one pair)
    constexpr int NPL = LEAF ? 3 : 1;         // u planes (hi only): [uL,uR,]u
    constexpr int UST = NPL * 2048;
    constexpr int FST = LEAF ? 3072 : 1024;   // frag planes per tile (hi-only, 1KB each)
    __shared__ __align__(16) char lds[2 * STG + 2 * UST + 2 * FST];
    char* ub  = lds + 2 * STG;
    char* fpl = ub + 2 * UST;

    const int lane = threadIdx.x & 63;
    const int w    = threadIdx.x >> 6;
    const int cidx = lane & 15;
    const int g    = lane >> 4;

    // ---- weight fragments (hi/lo), transposed orientation ----
    short8 WhH[6], WhL[6], WuH, WuL;
#pragma unroll
    for (int s = 0; s < 6; ++s) {
        union { short8 s8; unsigned u[4]; } H, L;
#pragma unroll
        for (int q = 0; q < 4; ++q) {
            const int k = 32 * s + 8 * g + 2 * q;
            split2(Wh[k * 64 + 16 * w + cidx], Wh[(k + 1) * 64 + 16 * w + cidx], H.u[q], L.u[q]);
        }
        WhH[s] = H.s8; WhL[s] = L.s8;
    }
    {
        union { short8 s8; unsigned u[4]; } H, L;
#pragma unroll
        for (int q = 0; q < 4; ++q) {
            const int k = 8 * g + 2 * q;
            split2(Wu[k * 64 + 16 * w + cidx], Wu[(k + 1) * 64 + 16 * w + cidx], H.u[q], L.u[q]);
        }
        WuH = H.s8; WuL = L.s8;
    }
    const f32x4 bu4 = *(const f32x4*)(bu + 16 * w + 4 * g);
    const f32x4 bh4 = *(const f32x4*)(bh + 16 * w + 4 * g);

    const char* eb = (const char*)ein_;
    const unsigned colb = 32u * w + 8u * g;
    const int S = gridDim.x;

    const int stile = w >> 1, sside = w & 1;   // staging share: (tile, side)
    const unsigned fo = (unsigned)g * 256u + (unsigned)cidx * 16u;  // 1KB plane slot
    const unsigned o0 = 512u * (g & 1) + 16u * cidx;                // fp32 x-frag
    const unsigned rg = (unsigned)(g >> 1) * 1024u;

    int p = blockIdx.x;
    const int p1 = (p + S < npairs) ? p + S : p;
    const int ps0 = LEAF ? ((p + 2 * S < npairs) ? p + 2 * S : p) : p1;

    int2 sA, sB;   // child rows of the pair staged at the next staging point

    // ---- prologue ----
    {
        const int2 cA = *(const int2*)(child + 2 * (2 * p * 16 + cidx));
        const int2 cB = *(const int2*)(child + 2 * ((2 * p + 1) * 16 + cidx));
        { int2 ch = stile ? cB : cA; const int c = sside ? ch.y : ch.x;
          char* d = lds + 0 * STG + stile * TS + sside * 2048;
          gld16(eb + (size_t)c * 128 +      g * 16, d);
          gld16(eb + (size_t)c * 128 + 64 + g * 16, d + 1024); }
        if (LEAF) {
            const int2 dA = *(const int2*)(child + 2 * (2 * p1 * 16 + cidx));
            const int2 dB = *(const int2*)(child + 2 * ((2 * p1 + 1) * 16 + cidx));
            int2 ch = stile ? dB : dA; const int c = sside ? ch.y : ch.x;
            char* d = lds + 1 * STG + stile * TS + sside * 2048;
            gld16(eb + (size_t)c * 128 +      g * 16, d);
            gld16(eb + (size_t)c * 128 + 64 + g * 16, d + 1024);
        }
        sA = *(const int2*)(child + 2 * (2 * ps0 * 16 + cidx));
        sB = *(const int2*)(child + 2 * ((2 * ps0 + 1) * 16 + cidx));
    }
    f32x4 c0, c1;
    if (w == 0) {
        const f32x4* pc = (const f32x4*)(cont + (size_t)(2 * p * 16 + cidx) * 32 + 8 * g);
        c0 = pc[0]; c1 = pc[1];
    } else if (w == (LEAF ? 2 : 1)) {
        const f32x4* pc = (const f32x4*)(cont + (size_t)((2 * p + 1) * 16 + cidx) * 32 + 8 * g);
        c0 = pc[0]; c1 = pc[1];
    }
    __syncthreads();   // full drain: prologue staging + regs complete

    // prologue frag jobs for pair p (hi-only packs)
    if (LEAF) {
        const int tt = w >> 1;
        if ((w & 1) == 0) {        // w0/w2: cont + xL of tile tt
            *(short8*)(fpl + tt * FST + fo) = pack8(c0, c1);
            const char* xb = lds + 0 * STG + tt * TS;
            const f32x4 a = *(const f32x4*)(xb + rg + o0);
            const f32x4 b = *(const f32x4*)(xb + rg + o0 + 256);
            *(short8*)(fpl + tt * FST + 1024 + fo) = pack8(a, b);
        } else {                    // w1/w3: xR of tile tt
            const char* xb = lds + 0 * STG + tt * TS + 2048;
            const f32x4 a = *(const f32x4*)(xb + rg + o0);
            const f32x4 b = *(const f32x4*)(xb + rg + o0 + 256);
            *(short8*)(fpl + tt * FST + 2048 + fo) = pack8(a, b);
        }
    } else if (w <= 1) {
        *(short8*)(fpl + w * FST + fo) = pack8(c0, c1);
    }
    __syncthreads();

    for (int k = 0; p < npairs; p += S, ++k) {
        const int pb = k & 1;
        const int pf = (p + S < npairs) ? p + S : p;
        const int pn = LEAF ? ((p + 3 * S < npairs) ? p + 3 * S : p)
                            : ((p + 2 * S < npairs) ? p + 2 * S : p);

        // ---- phase 1: u-GEMMs (2 MFMAs each) for both tiles; hi-only stash ----
#pragma unroll
        for (int tt = 0; tt < 2; ++tt) {
            const short8 aH = *(const short8*)(fpl + tt * FST + fo);
            f32x4 ua = bu4;
            ua = MFMA16(WuH, aH, ua);
            ua = MFMA16(WuL, aH, ua);
            const unsigned off = swz(cidx, colb);
            {
                unsigned h0 = pack2(fmaxf(ua[0], 0.f), fmaxf(ua[1], 0.f));
                unsigned h1 = pack2(fmaxf(ua[2], 0.f), fmaxf(ua[3], 0.f));
                *(uint2*)(ub + tt * UST + (NPL - 1) * 2048 + off) = uint2{h0, h1};
            }
            if (LEAF) {
#pragma unroll
                for (int sd = 0; sd < 2; ++sd) {
                    const short8 xH = *(const short8*)(fpl + tt * FST + (1 + sd) * 1024 + fo);
                    f32x4 ux = bu4;
                    ux = MFMA16(WuH, xH, ux);
                    ux = MFMA16(WuL, xH, ux);
                    unsigned h0 = pack2(fmaxf(ux[0], 0.f), fmaxf(ux[1], 0.f));
                    unsigned h1 = pack2(fmaxf(ux[2], 0.f), fmaxf(ux[3], 0.f));
                    *(uint2*)(ub + tt * UST + sd * 2048 + off) = uint2{h0, h1};
                }
            }
        }
        VM_WAIT0();      // ALL prior staging complete (canonical gld16 pattern)
        barrier_nv();    // A: staged buffers + u planes visible to all waves

        // ---- phase 2 ----
        if (w == 0) {
            const f32x4* pc = (const f32x4*)(cont + (size_t)(2 * pf * 16 + cidx) * 32 + 8 * g);
            c0 = pc[0]; c1 = pc[1];
        } else if (w == (LEAF ? 2 : 1)) {
            const f32x4* pc = (const f32x4*)(cont + (size_t)((2 * pf + 1) * 16 + cidx) * 32 + 8 * g);
            c0 = pc[0]; c1 = pc[1];
        }
        // stage next pair from pipelined child regs (128B-row form); drained
        // at the NEXT iteration's VM_WAIT0-before-A, consumed after that A.
        {
            int2 ch = stile ? sB : sA; const int c = sside ? ch.y : ch.x;
            char* d = lds + (LEAF ? pb : (pb ^ 1)) * STG + stile * TS + sside * 2048;
            gld16(eb + (size_t)c * 128 +      g * 16, d);
            gld16(eb + (size_t)c * 128 + 64 + g * 16, d + 1024);
        }
        __builtin_amdgcn_sched_barrier(0);
        int2 nA = *(const int2*)(child + 2 * (2 * pn * 16 + cidx));
        int2 nB = *(const int2*)(child + 2 * ((2 * pn + 1) * 16 + cidx));

        // h-GEMMs: every slot = 2 MFMAs (hi activation x hi/lo weight)
        f32x4 acc[2][2];
        acc[0][0] = bh4; acc[0][1] = f32x4{0.f, 0.f, 0.f, 0.f};
        acc[1][0] = bh4; acc[1][1] = f32x4{0.f, 0.f, 0.f, 0.f};
        if (LEAF) {
#pragma unroll
            for (int tt = 0; tt < 2; ++tt)
#pragma unroll
            for (int q = 0; q < 3; ++q)
#pragma unroll
            for (int s = 0; s < 2; ++s) {
                const short8 aH = *(const short8*)(ub + tt * UST + q * 2048 + swz(cidx, 64 * s + 16 * g));
                const int Sl = 2 * q + s;
                acc[tt][s] = MFMA16(WhH[Sl], aH, acc[tt][s]);
                acc[tt][s] = MFMA16(WhL[Sl], aH, acc[tt][s]);
            }
        } else {
#pragma unroll
            for (int tt = 0; tt < 2; ++tt) {
                const char* hb = lds + pb * STG + tt * TS;
#pragma unroll
                for (int sd = 0; sd < 2; ++sd)
#pragma unroll
                for (int s = 0; s < 2; ++s) {
                    const short8 aH = *(const short8*)(hb + sd * 2048 + s * 1024 + 16 * lane);
                    const int Sl = 2 * sd + s;
                    acc[tt][sd] = MFMA16(WhH[Sl], aH, acc[tt][sd]);
                    acc[tt][sd] = MFMA16(WhL[Sl], aH, acc[tt][sd]);
                }
#pragma unroll
                for (int s = 0; s < 2; ++s) {
                    const short8 aH = *(const short8*)(ub + tt * UST + swz(cidx, 64 * s + 16 * g));
                    const int Sl = 4 + s;
                    acc[tt][s] = MFMA16(WhH[Sl], aH, acc[tt][s]);
                    acc[tt][s] = MFMA16(WhL[Sl], aH, acc[tt][s]);
                }
            }
        }

        // frag jobs for pair pf (hi-only packs; staged x visible since last A)
        if (LEAF) {
            const char* xbase = lds + (pb ^ 1) * STG;
            const int tt = w >> 1;
            if ((w & 1) == 0) {        // w0/w2: cont + xL of tile tt
                *(short8*)(fpl + tt * FST + fo) = pack8(c0, c1);
                const char* xb = xbase + tt * TS;
                const f32x4 a = *(const f32x4*)(xb + rg + o0);
                const f32x4 b = *(const f32x4*)(xb + rg + o0 + 256);
                *(short8*)(fpl + tt * FST + 1024 + fo) = pack8(a, b);
            } else {                    // w1/w3: xR of tile tt
                const char* xb = xbase + tt * TS + 2048;
                const f32x4 a = *(const f32x4*)(xb + rg + o0);
                const f32x4 b = *(const f32x4*)(xb + rg + o0 + 256);
                *(short8*)(fpl + tt * FST + 2048 + fo) = pack8(a, b);
            }
        } else if (w <= 1) {
            *(short8*)(fpl + w * FST + fo) = pack8(c0, c1);
        }

        // ---- stores: tiles 2p, 2p+1 (bf16 128B rows; fp32 if FINAL) ----
#pragma unroll
        for (int tt = 0; tt < 2; ++tt) {
            const int T = 2 * p + tt;
            if (FINAL) {
                float* out = (float*)eout_;
                f32x4 v;
#pragma unroll
                for (int i = 0; i < 4; ++i) v[i] = fmaxf(acc[tt][0][i] + acc[tt][1][i], 0.f);
                *(f32x4*)(out + (size_t)(T * 16 + cidx) * 64 + 16 * w + 4 * g) = v;
            } else {
                char* out = (char*)eout_;
                const size_t rb = (size_t)(T * 16 + cidx) * 128;
                unsigned h0 = pack2(fmaxf(acc[tt][0][0] + acc[tt][1][0], 0.f),
                                    fmaxf(acc[tt][0][1] + acc[tt][1][1], 0.f));
                unsigned h1 = pack2(fmaxf(acc[tt][0][2] + acc[tt][1][2], 0.f),
                                    fmaxf(acc[tt][0][3] + acc[tt][1][3], 0.f));
                *(uint2*)(out + rb + colb) = uint2{h0, h1};
            }
        }
        barrier_nv();   // B: frag planes visible (ds ops only)
        sA = nA; sB = nB;
    }
}

extern "C" void kernel_launch(void* const* d_in, const int* in_sizes, int n_in,
                              void* d_out, int out_size, void* d_ws, size_t ws_size,
                              hipStream_t stream) {
    // inputs: contents0..8 = d_in[0..8], children0..7 = d_in[9..16],
    //         Wu = d_in[17], bu = d_in[18], Wh = d_in[19], bh = d_in[20]
    const float* Wu = (const float*)d_in[17];
    const float* bu = (const float*)d_in[18];
    const float* Wh = (const float*)d_in[19];
    const float* bh = (const float*)d_in[20];

    // emb_j stored as single-bf16 rows, 128B/row
    void* bufA = d_ws;                               // emb7/5/3/1
    void* bufB = (char*)d_ws + (size_t)268435456;    // emb6/4/2

    const void* ein = d_in[8];  // contents8 (fp32) for the fused leaf level
    for (int j = 7; j >= 0; --j) {
        const int n      = in_sizes[j] / 32;
        const int npairs = n / 32;
        void* eout = (j == 0) ? d_out : ((j & 1) ? bufA : bufB);
        int blocks = npairs < 4096 ? npairs : 4096;
        const float* cont  = (const float*)d_in[j];
        const int*   child = (const int*)d_in[9 + j];
        if (j == 7)
            grnn_mfma<true,  false><<<blocks, 256, 0, stream>>>(cont, child, ein, Wu, bu, Wh, bh, eout, npairs);
        else if (j == 0)
            grnn_mfma<false, true ><<<blocks, 256, 0, stream>>>(cont, child, ein, Wu, bu, Wh, bh, eout, npairs);
        else
            grnn_mfma<false, false><<<blocks, 256, 0, stream>>>(cont, child, ein, Wu, bu, Wh, bh, eout, npairs);
        ein = eout;
    }
}